// Round 3
// baseline (1464.686 us; speedup 1.0000x reference)
//
#include <hip/hip_runtime.h>

// 3-layer GCN on MI355X:  out = S(S(S x W0) W1) W2 = (S^3 x) (W0 W1 W2)
// S = scatter-add over E edges (dst <- src). N = 100000, E = 1200000, D = 64.
//
// Pipeline per launch (everything rebuilt each call; no cross-call state):
//   k_wchain : Wc = W0 @ W1 @ W2            (one block, LDS)
//   k_binhist: count edges per 64-row dst bin (LDS-aggregated)
//   k_binscan: exclusive scan of bin counts  (single block)
//   k_part   : partition (src,dst) pairs into per-bin segments
//   k_aggbin : per-bin LDS accumulator aggregation  (x -> h -> out -> h)
//   gcn_gemm64: out = h @ Wc

#define GCN_D 64
#define BINSHIFT 6
#define BINROWS 64          // dst rows per bin
#define MAXBINS 2048        // LDS histogram capacity
#define CPAD 16             // counter padding (ints) -> one 64B line per bin

// ---------------- GEMM: OUT[r,:] = X[r,:] @ W ----------------
__global__ __launch_bounds__(256) void gcn_gemm64(const float* __restrict__ X,
                                                  const float* __restrict__ W,
                                                  float* __restrict__ H,
                                                  int nrows) {
    __shared__ float Wl[64 * 64];
    __shared__ float Xl[16][65];

    const int tid = threadIdx.x;
    for (int i = tid; i < 1024; i += 256) ((float4*)Wl)[i] = ((const float4*)W)[i];

    const int rowBase = blockIdx.x * 16;
    const int lr = tid >> 4;
    const int lc = tid & 15;
    const int grow = rowBase + lr;

    if (grow < nrows) {
        float4 xv = ((const float4*)X)[(long long)grow * 16 + lc];
        Xl[lr][lc * 4 + 0] = xv.x;
        Xl[lr][lc * 4 + 1] = xv.y;
        Xl[lr][lc * 4 + 2] = xv.z;
        Xl[lr][lc * 4 + 3] = xv.w;
    }
    __syncthreads();

    float4 acc = make_float4(0.f, 0.f, 0.f, 0.f);
#pragma unroll
    for (int k = 0; k < 64; ++k) {
        const float xv = Xl[lr][k];
        const float4 w4 = ((const float4*)Wl)[k * 16 + lc];
        acc.x = fmaf(xv, w4.x, acc.x);
        acc.y = fmaf(xv, w4.y, acc.y);
        acc.z = fmaf(xv, w4.z, acc.z);
        acc.w = fmaf(xv, w4.w, acc.w);
    }
    if (grow < nrows) ((float4*)H)[(long long)grow * 16 + lc] = acc;
}

// ---------------- Wc = W0 @ W1 @ W2 (single block) ----------------
__global__ __launch_bounds__(256) void k_wchain(const float* __restrict__ W0,
                                                const float* __restrict__ W1,
                                                const float* __restrict__ W2,
                                                float* __restrict__ Wc) {
    __shared__ float A[4096], B[4096], T[4096];
    const int t = threadIdx.x;
    for (int i = t; i < 1024; i += 256) {
        ((float4*)A)[i] = ((const float4*)W0)[i];
        ((float4*)B)[i] = ((const float4*)W1)[i];
    }
    __syncthreads();
    // T = A @ B : each thread computes 4 float4 cells
#pragma unroll
    for (int g = 0; g < 4; ++g) {
        const int idx = t + 256 * g;        // float4 cell id 0..1023
        const int r = idx >> 4, c4 = idx & 15;
        float4 acc = make_float4(0.f, 0.f, 0.f, 0.f);
#pragma unroll
        for (int k = 0; k < 64; ++k) {
            const float a = A[r * 64 + k];
            const float4 b = ((float4*)B)[k * 16 + c4];
            acc.x = fmaf(a, b.x, acc.x); acc.y = fmaf(a, b.y, acc.y);
            acc.z = fmaf(a, b.z, acc.z); acc.w = fmaf(a, b.w, acc.w);
        }
        ((float4*)T)[idx] = acc;
    }
    __syncthreads();
    for (int i = t; i < 1024; i += 256) ((float4*)B)[i] = ((const float4*)W2)[i];
    __syncthreads();
    // Wc = T @ B
#pragma unroll
    for (int g = 0; g < 4; ++g) {
        const int idx = t + 256 * g;
        const int r = idx >> 4, c4 = idx & 15;
        float4 acc = make_float4(0.f, 0.f, 0.f, 0.f);
#pragma unroll
        for (int k = 0; k < 64; ++k) {
            const float a = T[r * 64 + k];
            const float4 b = ((float4*)B)[k * 16 + c4];
            acc.x = fmaf(a, b.x, acc.x); acc.y = fmaf(a, b.y, acc.y);
            acc.z = fmaf(a, b.z, acc.z); acc.w = fmaf(a, b.w, acc.w);
        }
        ((float4*)Wc)[idx] = acc;
    }
}

// ---------------- binning ----------------
__global__ __launch_bounds__(256) void k_binhist(const int* __restrict__ ei,
                                                 int* __restrict__ binCntP,
                                                 int E, int NB) {
    __shared__ int h[MAXBINS];
    const int t = threadIdx.x;
    for (int i = t; i < MAXBINS; i += 256) h[i] = 0;
    __syncthreads();
    for (int e = blockIdx.x * 256 + t; e < E; e += gridDim.x * 256)
        atomicAdd(&h[ei[E + e] >> BINSHIFT], 1);
    __syncthreads();
    for (int i = t; i < NB; i += 256) {
        const int c = h[i];
        if (c) atomicAdd(&binCntP[i * CPAD], c);
    }
}

// exclusive scan over NB (<= 2048) padded counts; writes binOff and rewrites
// binCntP[i*CPAD] = running offset (becomes the partition cursor).
__global__ __launch_bounds__(512) void k_binscan(int* __restrict__ binCntP,
                                                 int* __restrict__ binOff,
                                                 int NB) {
    __shared__ int sd[512];
    const int t = threadIdx.x;
    int v[4]; int s = 0;
#pragma unroll
    for (int j = 0; j < 4; ++j) {
        const int i = t * 4 + j;
        v[j] = (i < NB) ? binCntP[i * CPAD] : 0;
        s += v[j];
    }
    sd[t] = s; __syncthreads();
    int x = s;
    for (int off = 1; off < 512; off <<= 1) {
        const int y = (t >= off) ? sd[t - off] : 0;
        __syncthreads();
        x += y; sd[t] = x;
        __syncthreads();
    }
    int run = x - s;
#pragma unroll
    for (int j = 0; j < 4; ++j) {
        const int i = t * 4 + j;
        if (i < NB) { binOff[i] = run; binCntP[i * CPAD] = run; }
        run += v[j];
    }
    if (t == 511) binOff[NB] = x;
}

__global__ __launch_bounds__(256) void k_part(const int* __restrict__ ei,
                                              int* __restrict__ binCur,
                                              uint2* __restrict__ ebuf, int E) {
    const int e = blockIdx.x * 256 + threadIdx.x;
    if (e < E) {
        const int s = ei[e];
        const int d = ei[E + e];
        const int p = atomicAdd(&binCur[(d >> BINSHIFT) * CPAD], 1);
        ebuf[p] = make_uint2((unsigned)s, (unsigned)d);
    }
}

// ---------------- binned aggregation ----------------
// One block (512 thr = 8 waves) per bin of 64 dst rows. 16 KB LDS accumulator.
__global__ __launch_bounds__(512) void k_aggbin(const float* __restrict__ X,
                                                const uint2* __restrict__ ebuf,
                                                const int* __restrict__ binOff,
                                                float* __restrict__ out, int N) {
    __shared__ float acc[BINROWS][GCN_D];   // 16 KB
    const int t = threadIdx.x;
    for (int i = t; i < BINROWS * (GCN_D / 4); i += 512)
        ((float4*)acc)[i] = make_float4(0.f, 0.f, 0.f, 0.f);
    __syncthreads();

    const int b = blockIdx.x;
    const int e0 = binOff[b];
    const int e1 = binOff[b + 1];
    const int lane = t & 63;
    const int wid = t >> 6;                 // 0..7
    const int NW = 8;

    int e = e0 + wid;
    for (; e + 3 * NW < e1; e += 4 * NW) {
        const uint2 p0 = ebuf[e];
        const uint2 p1 = ebuf[e + NW];
        const uint2 p2 = ebuf[e + 2 * NW];
        const uint2 p3 = ebuf[e + 3 * NW];
        const float v0 = X[(size_t)p0.x * GCN_D + lane];
        const float v1 = X[(size_t)p1.x * GCN_D + lane];
        const float v2 = X[(size_t)p2.x * GCN_D + lane];
        const float v3 = X[(size_t)p3.x * GCN_D + lane];
        atomicAdd(&acc[p0.y & (BINROWS - 1)][lane], v0);
        atomicAdd(&acc[p1.y & (BINROWS - 1)][lane], v1);
        atomicAdd(&acc[p2.y & (BINROWS - 1)][lane], v2);
        atomicAdd(&acc[p3.y & (BINROWS - 1)][lane], v3);
    }
    for (; e < e1; e += NW) {
        const uint2 p = ebuf[e];
        const float v = X[(size_t)p.x * GCN_D + lane];
        atomicAdd(&acc[p.y & (BINROWS - 1)][lane], v);
    }
    __syncthreads();

    const int rowBase = b << BINSHIFT;
    for (int i = t; i < BINROWS * (GCN_D / 4); i += 512) {
        const int r = i >> 4;
        const int gr = rowBase + r;
        if (gr < N) ((float4*)out)[(size_t)gr * 16 + (i & 15)] = ((float4*)acc)[i];
    }
}

// ---------------- R1 fallback: atomic scatter ----------------
__global__ __launch_bounds__(256) void gcn_scatter(const float* __restrict__ H,
                                                   const int* __restrict__ ei,
                                                   float* __restrict__ out,
                                                   int nedges) {
    const long long t = (long long)blockIdx.x * 256 + threadIdx.x;
    const int e = (int)(t >> 4);
    if (e >= nedges) return;
    const int lc = (int)(t & 15);
    const int s = ei[e];
    const int d = ei[nedges + e];
    const float4 v = ((const float4*)H)[(long long)s * 16 + lc];
    float* o = out + (long long)d * GCN_D + lc * 4;
    atomicAdd(o + 0, v.x);
    atomicAdd(o + 1, v.y);
    atomicAdd(o + 2, v.z);
    atomicAdd(o + 3, v.w);
}

extern "C" void kernel_launch(void* const* d_in, const int* in_sizes, int n_in,
                              void* d_out, int out_size, void* d_ws, size_t ws_size,
                              hipStream_t stream) {
    const float* x  = (const float*)d_in[0];
    const int*   ei = (const int*)d_in[1];   // [2,E] flat: src then dst (int32)
    const float* W0 = (const float*)d_in[2];
    const float* W1 = (const float*)d_in[3];
    const float* W2 = (const float*)d_in[4];
    float* out = (float*)d_out;

    const int N_ = in_sizes[0] / GCN_D;
    const int E_ = in_sizes[1] / 2;
    const int NB = (N_ + BINROWS - 1) / BINROWS;

    // ws layout: h | Wc | binOff | binCntP | (align8) ebuf
    float* h    = (float*)d_ws;
    float* Wc   = h + (size_t)N_ * GCN_D;
    int* binOff = (int*)(Wc + 4096);
    int* binCntP = binOff + (NB + 1);
    uintptr_t ebase = (uintptr_t)(binCntP + (size_t)NB * CPAD);
    ebase = (ebase + 7) & ~(uintptr_t)7;
    uint2* ebuf = (uint2*)ebase;
    const size_t needed = (ebase - (uintptr_t)d_ws) + (size_t)E_ * 8;

    const int gemmBlocks = (N_ + 15) / 16;
    const int edgeBlocks = (E_ + 255) / 256;

    if (NB <= MAXBINS && ws_size >= needed) {
        k_wchain<<<1, 256, 0, stream>>>(W0, W1, W2, Wc);
        hipMemsetAsync(binCntP, 0, (size_t)NB * CPAD * 4, stream);
        k_binhist<<<128, 256, 0, stream>>>(ei, binCntP, E_, NB);
        k_binscan<<<1, 512, 0, stream>>>(binCntP, binOff, NB);
        k_part<<<edgeBlocks, 256, 0, stream>>>(ei, binCntP, ebuf, E_);

        k_aggbin<<<NB, 512, 0, stream>>>(x,   ebuf, binOff, h,   N_);  // a1 = S x
        k_aggbin<<<NB, 512, 0, stream>>>(h,   ebuf, binOff, out, N_);  // a2 = S a1
        k_aggbin<<<NB, 512, 0, stream>>>(out, ebuf, binOff, h,   N_);  // a3 = S a2
        gcn_gemm64<<<gemmBlocks, 256, 0, stream>>>(h, Wc, out, N_);    // out = a3 Wc
    } else {
        // Fallback: R1 path (h only).
        const int scatBlocks = (int)(((long long)E_ * 16 + 255) / 256);
        const float* curAct = x;
        for (int l = 0; l < 3; ++l) {
            const float* Wl = (l == 0) ? W0 : (l == 1) ? W1 : W2;
            gcn_gemm64<<<gemmBlocks, 256, 0, stream>>>(curAct, Wl, h, N_);
            hipMemsetAsync(out, 0, (size_t)N_ * GCN_D * sizeof(float), stream);
            gcn_scatter<<<scatBlocks, 256, 0, stream>>>(h, ei, out, E_);
            curAct = out;
        }
    }
}

// Round 4
// 337.149 us; speedup vs baseline: 4.3443x; 4.3443x over previous
//
#include <hip/hip_runtime.h>

// 3-layer GCN on MI355X:  out = S^3(x) · (W0 W1 W2),  S = scatter-add over E edges.
// N = 100000, E = 1200000, D = 64.
//
// Per launch (no cross-call state):
//   k_wchain : Wc = W0 @ W1 @ W2                       (1 block)
//   memset head = -1 ; k_build: per-dst linked list    (dense writes, no sort)
//   k_agg4 x3: walk chains, float4 gathers, reg accum  (x -> h -> out -> h)
//   gcn_gemm64: out = h @ Wc

#define GCN_D 64

// ---------------- GEMM: OUT[r,:] = X[r,:] @ W ----------------
__global__ __launch_bounds__(256) void gcn_gemm64(const float* __restrict__ X,
                                                  const float* __restrict__ W,
                                                  float* __restrict__ H,
                                                  int nrows) {
    __shared__ float Wl[64 * 64];
    __shared__ float Xl[16][65];

    const int tid = threadIdx.x;
    for (int i = tid; i < 1024; i += 256) ((float4*)Wl)[i] = ((const float4*)W)[i];

    const int rowBase = blockIdx.x * 16;
    const int lr = tid >> 4;
    const int lc = tid & 15;
    const int grow = rowBase + lr;

    if (grow < nrows) {
        float4 xv = ((const float4*)X)[(long long)grow * 16 + lc];
        Xl[lr][lc * 4 + 0] = xv.x;
        Xl[lr][lc * 4 + 1] = xv.y;
        Xl[lr][lc * 4 + 2] = xv.z;
        Xl[lr][lc * 4 + 3] = xv.w;
    }
    __syncthreads();

    float4 acc = make_float4(0.f, 0.f, 0.f, 0.f);
#pragma unroll
    for (int k = 0; k < 64; ++k) {
        const float xv = Xl[lr][k];
        const float4 w4 = ((const float4*)Wl)[k * 16 + lc];
        acc.x = fmaf(xv, w4.x, acc.x);
        acc.y = fmaf(xv, w4.y, acc.y);
        acc.z = fmaf(xv, w4.z, acc.z);
        acc.w = fmaf(xv, w4.w, acc.w);
    }
    if (grow < nrows) ((float4*)H)[(long long)grow * 16 + lc] = acc;
}

// ---------------- Wc = W0 @ W1 @ W2 (single block) ----------------
__global__ __launch_bounds__(256) void k_wchain(const float* __restrict__ W0,
                                                const float* __restrict__ W1,
                                                const float* __restrict__ W2,
                                                float* __restrict__ Wc) {
    __shared__ float A[4096], B[4096], T[4096];
    const int t = threadIdx.x;
    for (int i = t; i < 1024; i += 256) {
        ((float4*)A)[i] = ((const float4*)W0)[i];
        ((float4*)B)[i] = ((const float4*)W1)[i];
    }
    __syncthreads();
#pragma unroll
    for (int g = 0; g < 4; ++g) {
        const int idx = t + 256 * g;
        const int r = idx >> 4, c4 = idx & 15;
        float4 acc = make_float4(0.f, 0.f, 0.f, 0.f);
#pragma unroll
        for (int k = 0; k < 64; ++k) {
            const float a = A[r * 64 + k];
            const float4 b = ((float4*)B)[k * 16 + c4];
            acc.x = fmaf(a, b.x, acc.x); acc.y = fmaf(a, b.y, acc.y);
            acc.z = fmaf(a, b.z, acc.z); acc.w = fmaf(a, b.w, acc.w);
        }
        ((float4*)T)[idx] = acc;
    }
    __syncthreads();
    for (int i = t; i < 1024; i += 256) ((float4*)B)[i] = ((const float4*)W2)[i];
    __syncthreads();
#pragma unroll
    for (int g = 0; g < 4; ++g) {
        const int idx = t + 256 * g;
        const int r = idx >> 4, c4 = idx & 15;
        float4 acc = make_float4(0.f, 0.f, 0.f, 0.f);
#pragma unroll
        for (int k = 0; k < 64; ++k) {
            const float a = T[r * 64 + k];
            const float4 b = ((float4*)B)[k * 16 + c4];
            acc.x = fmaf(a, b.x, acc.x); acc.y = fmaf(a, b.y, acc.y);
            acc.z = fmaf(a, b.z, acc.z); acc.w = fmaf(a, b.w, acc.w);
        }
        ((float4*)Wc)[idx] = acc;
    }
}

// ---------------- Linked-list build ----------------
// head[d] <- e, next[e] <- old head. Dense next writes; head is a hot 400 KB
// region (L2-resident, lines merge) -> no partial-line HBM RMW storm.
__global__ __launch_bounds__(256) void k_build(const int* __restrict__ ei,
                                               unsigned* __restrict__ head,
                                               unsigned* __restrict__ nxt, int E) {
    const int e = blockIdx.x * 256 + threadIdx.x;
    if (e < E) {
        const int d = ei[E + e];
        const unsigned old = atomicExch(&head[d], (unsigned)e);
        nxt[e] = old;   // safe: no reader until next kernel (launch boundary)
    }
}

// ---------------- Aggregation: out[r,:] = sum over r's chain of X[src,:] ----
// 1 wave = 8 rows: 4 quarters (16 lanes) x 2 chained walks each.
// Each quarter gathers full 256 B rows as float4 (64 lanes x 16 B = 1 KB/instr),
// accumulates in registers. 8 independent gathers in flight per wave.
__global__ __launch_bounds__(256) void k_agg4(const float* __restrict__ X,
                                              const int* __restrict__ esrc,
                                              const unsigned* __restrict__ head,
                                              const unsigned* __restrict__ nxt,
                                              float* __restrict__ out, int N) {
    const int t = threadIdx.x;
    const int gw = (blockIdx.x * 256 + t) >> 6;   // global wave id
    const int lane = t & 63;
    const int q = lane >> 4;                      // quarter 0..3
    const int f4 = lane & 15;                     // float4 slot within row
    const int r0 = gw * 8 + q * 2;
    const int r1 = r0 + 1;

    unsigned p0 = (r0 < N) ? head[r0] : 0xFFFFFFFFu;
    unsigned p1 = (r1 < N) ? head[r1] : 0xFFFFFFFFu;
    float4 a0 = make_float4(0.f, 0.f, 0.f, 0.f);
    float4 a1 = make_float4(0.f, 0.f, 0.f, 0.f);

    while (__any((p0 != 0xFFFFFFFFu) || (p1 != 0xFFFFFFFFu))) {
        if (p0 != 0xFFFFFFFFu) {
            const unsigned n = nxt[p0];
            const int s = esrc[p0];
            const float4 v = ((const float4*)X)[(size_t)s * 16 + f4];
            a0.x += v.x; a0.y += v.y; a0.z += v.z; a0.w += v.w;
            p0 = n;
        }
        if (p1 != 0xFFFFFFFFu) {
            const unsigned n = nxt[p1];
            const int s = esrc[p1];
            const float4 v = ((const float4*)X)[(size_t)s * 16 + f4];
            a1.x += v.x; a1.y += v.y; a1.z += v.z; a1.w += v.w;
            p1 = n;
        }
    }
    if (r0 < N) ((float4*)out)[(size_t)r0 * 16 + f4] = a0;
    if (r1 < N) ((float4*)out)[(size_t)r1 * 16 + f4] = a1;
}

// ---------------- R1 fallback: atomic scatter ----------------
__global__ __launch_bounds__(256) void gcn_scatter(const float* __restrict__ H,
                                                   const int* __restrict__ ei,
                                                   float* __restrict__ out,
                                                   int nedges) {
    const long long t = (long long)blockIdx.x * 256 + threadIdx.x;
    const int e = (int)(t >> 4);
    if (e >= nedges) return;
    const int lc = (int)(t & 15);
    const int s = ei[e];
    const int d = ei[nedges + e];
    const float4 v = ((const float4*)H)[(long long)s * 16 + lc];
    float* o = out + (long long)d * GCN_D + lc * 4;
    atomicAdd(o + 0, v.x);
    atomicAdd(o + 1, v.y);
    atomicAdd(o + 2, v.z);
    atomicAdd(o + 3, v.w);
}

extern "C" void kernel_launch(void* const* d_in, const int* in_sizes, int n_in,
                              void* d_out, int out_size, void* d_ws, size_t ws_size,
                              hipStream_t stream) {
    const float* x  = (const float*)d_in[0];
    const int*   ei = (const int*)d_in[1];   // [2,E] flat: src then dst (int32)
    const float* W0 = (const float*)d_in[2];
    const float* W1 = (const float*)d_in[3];
    const float* W2 = (const float*)d_in[4];
    float* out = (float*)d_out;

    const int N_ = in_sizes[0] / GCN_D;
    const int E_ = in_sizes[1] / 2;

    // ws layout: h | Wc | head | next
    float*    h    = (float*)d_ws;
    float*    Wc   = h + (size_t)N_ * GCN_D;
    unsigned* head = (unsigned*)(Wc + 4096);
    unsigned* nxt  = head + N_;
    const size_t needed = (size_t)N_ * GCN_D * 4 + 4096 * 4
                        + (size_t)N_ * 4 + (size_t)E_ * 4;

    const int gemmBlocks = (N_ + 15) / 16;
    const int edgeBlocks = (E_ + 255) / 256;

    if (ws_size >= needed) {
        k_wchain<<<1, 256, 0, stream>>>(W0, W1, W2, Wc);
        hipMemsetAsync(head, 0xFF, (size_t)N_ * 4, stream);
        k_build<<<edgeBlocks, 256, 0, stream>>>(ei, head, nxt, E_);

        const int waves = (N_ + 7) / 8;            // 8 rows per wave
        const int aggBlocks = (waves + 3) / 4;     // 4 waves per block
        k_agg4<<<aggBlocks, 256, 0, stream>>>(x,   ei, head, nxt, h,   N_);
        k_agg4<<<aggBlocks, 256, 0, stream>>>(h,   ei, head, nxt, out, N_);
        k_agg4<<<aggBlocks, 256, 0, stream>>>(out, ei, head, nxt, h,   N_);
        gcn_gemm64<<<gemmBlocks, 256, 0, stream>>>(h, Wc, out, N_);
    } else {
        // Fallback: R1 path (needs only h = N*64 f32).
        const int scatBlocks = (int)(((long long)E_ * 16 + 255) / 256);
        const float* curAct = x;
        for (int l = 0; l < 3; ++l) {
            const float* Wl = (l == 0) ? W0 : (l == 1) ? W1 : W2;
            gcn_gemm64<<<gemmBlocks, 256, 0, stream>>>(curAct, Wl, h, N_);
            hipMemsetAsync(out, 0, (size_t)N_ * GCN_D * sizeof(float), stream);
            gcn_scatter<<<scatBlocks, 256, 0, stream>>>(h, ei, out, E_);
            curAct = out;
        }
    }
}

// Round 6
// 297.483 us; speedup vs baseline: 4.9236x; 1.1333x over previous
//
#include <hip/hip_runtime.h>

// 3-layer GCN on MI355X:  out = S^3(x) · (W0 W1 W2),  S = scatter-add over E edges.
// N = 100000, E = 1200000, D = 64.
//
// Per launch (no cross-call state):
//   k_wchain : Wc = W0 @ W1 @ W2                        (1 block)
//   k_tobf   : B0 = bf16(x)                             (halves gather bytes)
//   k_build  : per-dst linked list + degree counts      (dense writes)
//   scan     : rp = exclusive prefix of counts
//   k_flat   : walk chains once -> dense dst-sorted cs  (scattered reads, once)
//   k_aggc x3: stream cs, gather bf16 rows, f32 accum, write bf16
//   gcn_gemm64b: out = bf16(a3) @ Wc  (f32 out)

#define GCN_D 64

typedef unsigned short ushort;

__device__ __forceinline__ float bf2f(ushort u) {
    union { unsigned u; float f; } c; c.u = ((unsigned)u) << 16; return c.f;
}
// RNE f32 -> bf16 (finite inputs): add 0x7FFF + lsb(bit16), truncate.
__device__ __forceinline__ ushort f2bf(float f) {
    union { float f; unsigned u; } c; c.f = f;
    const unsigned r = 0x7FFFu + ((c.u >> 16) & 1u);
    return (ushort)((c.u + r) >> 16);
}

// ---------------- Wc = W0 @ W1 @ W2 (single block) ----------------
__global__ __launch_bounds__(256) void k_wchain(const float* __restrict__ W0,
                                                const float* __restrict__ W1,
                                                const float* __restrict__ W2,
                                                float* __restrict__ Wc) {
    __shared__ float A[4096], B[4096], T[4096];
    const int t = threadIdx.x;
    for (int i = t; i < 1024; i += 256) {
        ((float4*)A)[i] = ((const float4*)W0)[i];
        ((float4*)B)[i] = ((const float4*)W1)[i];
    }
    __syncthreads();
#pragma unroll
    for (int g = 0; g < 4; ++g) {
        const int idx = t + 256 * g;
        const int r = idx >> 4, c4 = idx & 15;
        float4 acc = make_float4(0.f, 0.f, 0.f, 0.f);
#pragma unroll
        for (int k = 0; k < 64; ++k) {
            const float a = A[r * 64 + k];
            const float4 b = ((float4*)B)[k * 16 + c4];
            acc.x = fmaf(a, b.x, acc.x); acc.y = fmaf(a, b.y, acc.y);
            acc.z = fmaf(a, b.z, acc.z); acc.w = fmaf(a, b.w, acc.w);
        }
        ((float4*)T)[idx] = acc;
    }
    __syncthreads();
    for (int i = t; i < 1024; i += 256) ((float4*)B)[i] = ((const float4*)W2)[i];
    __syncthreads();
#pragma unroll
    for (int g = 0; g < 4; ++g) {
        const int idx = t + 256 * g;
        const int r = idx >> 4, c4 = idx & 15;
        float4 acc = make_float4(0.f, 0.f, 0.f, 0.f);
#pragma unroll
        for (int k = 0; k < 64; ++k) {
            const float a = T[r * 64 + k];
            const float4 b = ((float4*)B)[k * 16 + c4];
            acc.x = fmaf(a, b.x, acc.x); acc.y = fmaf(a, b.y, acc.y);
            acc.z = fmaf(a, b.z, acc.z); acc.w = fmaf(a, b.w, acc.w);
        }
        ((float4*)Wc)[idx] = acc;
    }
}

// ---------------- f32 -> bf16 convert (streaming) ----------------
__global__ __launch_bounds__(256) void k_tobf(const float* __restrict__ X,
                                              ushort* __restrict__ B, long long n4) {
    const long long stride = (long long)gridDim.x * 256;
    for (long long i = blockIdx.x * 256ll + threadIdx.x; i < n4; i += stride) {
        const float4 v = ((const float4*)X)[i];
        ushort4 u;
        u.x = f2bf(v.x); u.y = f2bf(v.y); u.z = f2bf(v.z); u.w = f2bf(v.w);
        ((ushort4*)B)[i] = u;
    }
}

// ---------------- Linked-list build + degree count ----------------
__global__ __launch_bounds__(256) void k_build(const int* __restrict__ ei,
                                               unsigned* __restrict__ head,
                                               unsigned* __restrict__ nxt,
                                               int* __restrict__ cnt, int E) {
    const int e = blockIdx.x * 256 + threadIdx.x;
    if (e < E) {
        const int d = ei[E + e];
        const unsigned old = atomicExch(&head[d], (unsigned)e);
        nxt[e] = old;
        atomicAdd(&cnt[d], 1);
    }
}

// ---------------- exclusive scan (1024 elems/block) ----------------
__global__ __launch_bounds__(256) void k_scan1(const int* __restrict__ in, int* __restrict__ out,
                                               int* __restrict__ bsum, int n) {
    __shared__ int sd[256];
    const int t = threadIdx.x;
    const int base = blockIdx.x * 1024 + t * 4;
    int v[4]; int s = 0;
#pragma unroll
    for (int j = 0; j < 4; ++j) { v[j] = (base + j < n) ? in[base + j] : 0; s += v[j]; }
    sd[t] = s; __syncthreads();
    int x = s;
    for (int off = 1; off < 256; off <<= 1) {
        int y = (t >= off) ? sd[t - off] : 0;
        __syncthreads();
        x += y; sd[t] = x;
        __syncthreads();
    }
    int run = x - s;
#pragma unroll
    for (int j = 0; j < 4; ++j) {
        if (base + j < n) out[base + j] = run;
        run += v[j];
    }
    if (t == 255) bsum[blockIdx.x] = x;
}

__global__ __launch_bounds__(256) void k_scan2(int* __restrict__ bsum, int nblk) {
    __shared__ int sd[256];
    const int t = threadIdx.x;
    int v = (t < nblk) ? bsum[t] : 0;
    sd[t] = v; __syncthreads();
    int x = v;
    for (int off = 1; off < 256; off <<= 1) {
        int y = (t >= off) ? sd[t - off] : 0;
        __syncthreads();
        x += y; sd[t] = x;
        __syncthreads();
    }
    if (t < nblk) bsum[t] = x - v;
}

__global__ __launch_bounds__(256) void k_scan3(int* __restrict__ rp, const int* __restrict__ bsum, int n) {
    const int t = threadIdx.x;
    const int off = bsum[blockIdx.x];
    const int base = blockIdx.x * 1024 + t * 4;
#pragma unroll
    for (int j = 0; j < 4; ++j) {
        const int i = base + j;
        if (i < n) rp[i] += off;
    }
}

// ---------------- Flatten: chains -> dense dst-sorted cs ----------------
__global__ __launch_bounds__(256) void k_flat(const unsigned* __restrict__ head,
                                              const unsigned* __restrict__ nxt,
                                              const int* __restrict__ esrc,
                                              const int* __restrict__ rp,
                                              int* __restrict__ cs, int N) {
    const int r = blockIdx.x * 256 + threadIdx.x;
    if (r >= N) return;
    int pos = rp[r];
    unsigned p = head[r];
    while (p != 0xFFFFFFFFu) {
        cs[pos++] = esrc[p];
        p = nxt[p];
    }
}

// ---------------- Aggregation: out[r,:] = sum_{e in row r} B[cs[e],:] ----
// 1 wave = 4 rows (16-lane quarter each). bf16 rows: lane reads ushort4 (8 B),
// 16 lanes x 8 B = 128 B per gather instr. 4-deep unroll -> 16 gathers in
// flight per wave. f32 accumulate, bf16 RNE write (dense 128 B row).
__global__ __launch_bounds__(256) void k_aggc(const ushort* __restrict__ B,
                                              const int* __restrict__ rp,
                                              const int* __restrict__ cs,
                                              ushort* __restrict__ out, int N) {
    const int t = threadIdx.x;
    const int gw = (blockIdx.x * 256 + t) >> 6;   // global wave id
    const int lane = t & 63;
    const int q = lane >> 4;                      // quarter 0..3
    const int f4 = lane & 15;                     // ushort4 slot in row
    const int r = gw * 4 + q;
    if (r >= N) return;

    const int e0 = rp[r];
    const int e1 = rp[r + 1];
    const ushort4* Bv = (const ushort4*)B;

    float4 acc = make_float4(0.f, 0.f, 0.f, 0.f);
    int e = e0;
    for (; e + 3 < e1; e += 4) {
        const int s0 = cs[e], s1 = cs[e + 1], s2 = cs[e + 2], s3 = cs[e + 3];
        const ushort4 u0 = Bv[(size_t)s0 * 16 + f4];
        const ushort4 u1 = Bv[(size_t)s1 * 16 + f4];
        const ushort4 u2 = Bv[(size_t)s2 * 16 + f4];
        const ushort4 u3 = Bv[(size_t)s3 * 16 + f4];
        acc.x += bf2f(u0.x) + bf2f(u1.x) + bf2f(u2.x) + bf2f(u3.x);
        acc.y += bf2f(u0.y) + bf2f(u1.y) + bf2f(u2.y) + bf2f(u3.y);
        acc.z += bf2f(u0.z) + bf2f(u1.z) + bf2f(u2.z) + bf2f(u3.z);
        acc.w += bf2f(u0.w) + bf2f(u1.w) + bf2f(u2.w) + bf2f(u3.w);
    }
    for (; e < e1; ++e) {
        const ushort4 u = Bv[(size_t)cs[e] * 16 + f4];
        acc.x += bf2f(u.x); acc.y += bf2f(u.y);
        acc.z += bf2f(u.z); acc.w += bf2f(u.w);
    }
    ushort4 o;
    o.x = f2bf(acc.x); o.y = f2bf(acc.y); o.z = f2bf(acc.z); o.w = f2bf(acc.w);
    ((ushort4*)out)[(size_t)r * 16 + f4] = o;
}

// ---------------- GEMM (bf16 input): OUT[r,:] = X[r,:] @ W ----------------
__global__ __launch_bounds__(256) void gcn_gemm64b(const ushort* __restrict__ X,
                                                   const float* __restrict__ W,
                                                   float* __restrict__ H,
                                                   int nrows) {
    __shared__ float Wl[64 * 64];
    __shared__ float Xl[16][65];

    const int tid = threadIdx.x;
    for (int i = tid; i < 1024; i += 256) ((float4*)Wl)[i] = ((const float4*)W)[i];

    const int rowBase = blockIdx.x * 16;
    const int lr = tid >> 4;
    const int lc = tid & 15;
    const int grow = rowBase + lr;

    if (grow < nrows) {
        const ushort4 u = ((const ushort4*)X)[(size_t)grow * 16 + lc];
        Xl[lr][lc * 4 + 0] = bf2f(u.x);
        Xl[lr][lc * 4 + 1] = bf2f(u.y);
        Xl[lr][lc * 4 + 2] = bf2f(u.z);
        Xl[lr][lc * 4 + 3] = bf2f(u.w);
    }
    __syncthreads();

    float4 acc = make_float4(0.f, 0.f, 0.f, 0.f);
#pragma unroll
    for (int k = 0; k < 64; ++k) {
        const float xv = Xl[lr][k];
        const float4 w4 = ((const float4*)Wl)[k * 16 + lc];
        acc.x = fmaf(xv, w4.x, acc.x);
        acc.y = fmaf(xv, w4.y, acc.y);
        acc.z = fmaf(xv, w4.z, acc.z);
        acc.w = fmaf(xv, w4.w, acc.w);
    }
    if (grow < nrows) ((float4*)H)[(size_t)grow * 16 + lc] = acc;
}

// ---------------- R1 fallback kernels ----------------
__global__ __launch_bounds__(256) void gcn_gemm64(const float* __restrict__ X,
                                                  const float* __restrict__ W,
                                                  float* __restrict__ H,
                                                  int nrows) {
    __shared__ float Wl[64 * 64];
    __shared__ float Xl[16][65];
    const int tid = threadIdx.x;
    for (int i = tid; i < 1024; i += 256) ((float4*)Wl)[i] = ((const float4*)W)[i];
    const int rowBase = blockIdx.x * 16;
    const int lr = tid >> 4;
    const int lc = tid & 15;
    const int grow = rowBase + lr;
    if (grow < nrows) {
        float4 xv = ((const float4*)X)[(long long)grow * 16 + lc];
        Xl[lr][lc * 4 + 0] = xv.x; Xl[lr][lc * 4 + 1] = xv.y;
        Xl[lr][lc * 4 + 2] = xv.z; Xl[lr][lc * 4 + 3] = xv.w;
    }
    __syncthreads();
    float4 acc = make_float4(0.f, 0.f, 0.f, 0.f);
#pragma unroll
    for (int k = 0; k < 64; ++k) {
        const float xv = Xl[lr][k];
        const float4 w4 = ((const float4*)Wl)[k * 16 + lc];
        acc.x = fmaf(xv, w4.x, acc.x); acc.y = fmaf(xv, w4.y, acc.y);
        acc.z = fmaf(xv, w4.z, acc.z); acc.w = fmaf(xv, w4.w, acc.w);
    }
    if (grow < nrows) ((float4*)H)[(long long)grow * 16 + lc] = acc;
}

__global__ __launch_bounds__(256) void gcn_scatter(const float* __restrict__ H,
                                                   const int* __restrict__ ei,
                                                   float* __restrict__ out,
                                                   int nedges) {
    const long long t = (long long)blockIdx.x * 256 + threadIdx.x;
    const int e = (int)(t >> 4);
    if (e >= nedges) return;
    const int lc = (int)(t & 15);
    const int s = ei[e];
    const int d = ei[nedges + e];
    const float4 v = ((const float4*)H)[(long long)s * 16 + lc];
    float* o = out + (long long)d * GCN_D + lc * 4;
    atomicAdd(o + 0, v.x);
    atomicAdd(o + 1, v.y);
    atomicAdd(o + 2, v.z);
    atomicAdd(o + 3, v.w);
}

extern "C" void kernel_launch(void* const* d_in, const int* in_sizes, int n_in,
                              void* d_out, int out_size, void* d_ws, size_t ws_size,
                              hipStream_t stream) {
    const float* x  = (const float*)d_in[0];
    const int*   ei = (const int*)d_in[1];   // [2,E] flat: src then dst (int32)
    const float* W0 = (const float*)d_in[2];
    const float* W1 = (const float*)d_in[3];
    const float* W2 = (const float*)d_in[4];
    float* out = (float*)d_out;

    const int N_ = in_sizes[0] / GCN_D;
    const int E_ = in_sizes[1] / 2;
    const int n  = N_ + 1;                   // scan length
    const int nblk = (n + 1023) / 1024;

    // ws layout (16 B aligned chunks):
    //   B0 | rp | cnt | bsum | Wc | cs | head | nxt
    //   B1 aliases [head ...] (head/nxt dead after k_flat)
    uintptr_t base = (uintptr_t)d_ws;
    ushort* B0   = (ushort*)base;                       // N*64 bf16 = 12.8 MB
    int*    rp   = (int*)(B0 + (size_t)N_ * GCN_D);     // n ints
    int*    cnt  = rp + ((n + 3) & ~3);
    int*    bsum = cnt + ((n + 3) & ~3);
    float*  Wc   = (float*)(bsum + 256);
    int*    cs   = (int*)(Wc + 4096);                   // E ints
    unsigned* head = (unsigned*)(cs + ((E_ + 3) & ~3)); // N
    unsigned* nxt  = head + ((N_ + 3) & ~3);            // E
    ushort* B1   = (ushort*)head;                       // N*64 bf16, aliases head/nxt+
    const uintptr_t endA = (uintptr_t)(nxt + E_);
    const uintptr_t endB = (uintptr_t)(B1 + (size_t)N_ * GCN_D);
    const size_t needed = ((endA > endB ? endA : endB) - base);

    const int gemmBlocks = (N_ + 15) / 16;
    const int edgeBlocks = (E_ + 255) / 256;

    if (ws_size >= needed && nblk <= 256) {
        k_wchain<<<1, 256, 0, stream>>>(W0, W1, W2, Wc);
        k_tobf<<<1024, 256, 0, stream>>>(x, B0, (long long)N_ * 16);
        hipMemsetAsync(head, 0xFF, (size_t)N_ * 4, stream);
        hipMemsetAsync(cnt, 0, (size_t)n * 4, stream);
        k_build<<<edgeBlocks, 256, 0, stream>>>(ei, head, nxt, cnt, E_);
        k_scan1<<<nblk, 256, 0, stream>>>(cnt, rp, bsum, n);
        k_scan2<<<1, 256, 0, stream>>>(bsum, nblk);
        k_scan3<<<nblk, 256, 0, stream>>>(rp, bsum, n);
        k_flat<<<(N_ + 255) / 256, 256, 0, stream>>>(head, nxt, ei, rp, cs, N_);

        const int aggBlocks = (N_ + 15) / 16;           // 4 rows/wave, 4 waves/block
        k_aggc<<<aggBlocks, 256, 0, stream>>>(B0, rp, cs, B1, N_);   // a1
        k_aggc<<<aggBlocks, 256, 0, stream>>>(B1, rp, cs, B0, N_);   // a2
        k_aggc<<<aggBlocks, 256, 0, stream>>>(B0, rp, cs, B1, N_);   // a3
        gcn_gemm64b<<<gemmBlocks, 256, 0, stream>>>(B1, Wc, out, N_);
    } else {
        // Fallback: R1 path (needs only h = N*64 f32).
        float* h = (float*)d_ws;
        const int scatBlocks = (int)(((long long)E_ * 16 + 255) / 256);
        const float* curAct = x;
        for (int l = 0; l < 3; ++l) {
            const float* Wl = (l == 0) ? W0 : (l == 1) ? W1 : W2;
            gcn_gemm64<<<gemmBlocks, 256, 0, stream>>>(curAct, Wl, h, N_);
            hipMemsetAsync(out, 0, (size_t)N_ * GCN_D * sizeof(float), stream);
            gcn_scatter<<<scatBlocks, 256, 0, stream>>>(h, ei, out, E_);
            curAct = out;
        }
    }
}

// Round 7
// 189.547 us; speedup vs baseline: 7.7273x; 1.5694x over previous
//
#include <hip/hip_runtime.h>

// 3-layer GCN on MI355X:  out = S^3(x) · (W0 W1 W2),  S = scatter-add over E edges.
// N = 100000, E = 1200000, D = 64.
//
// Per launch (no cross-call state):
//   k_wchain : Wc = W0 @ W1 @ W2                     (1 block)
//   k_tobf   : B0 = bf16(x)
//   k_a0/k_ascan: 256-row segment histogram + scan   (LDS-aggregated)
//   k_apart  : LDS counting-sort blocks of 4096 edges -> per-segment (src,dst)
//              runs copied to global cursors (dense writes, no per-edge
//              global atomics -- k_build's 79.5 MB line-RMW storm removed)
//   k_bplace : per-segment LDS counting sort -> rp (CSR offsets) + cs (srcs)
//   k_aggc x3: stream cs, gather bf16 rows, f32 accum, write bf16
//   gcn_gemm64b: out = bf16(a3) @ Wc  (f32 out)

#define GCN_D 64
#define SEGSHIFT 8
#define SEGROWS 256          // dst rows per segment
#define MAXSEG 512           // compile-time LDS capacity (N <= 131072)
#define A_EPB 4096           // edges per k_apart block

typedef unsigned short ushort;

__device__ __forceinline__ float bf2f(ushort u) {
    union { unsigned u; float f; } c; c.u = ((unsigned)u) << 16; return c.f;
}
// RNE f32 -> bf16 (finite inputs): add 0x7FFF + lsb(bit16), truncate.
__device__ __forceinline__ ushort f2bf(float f) {
    union { float f; unsigned u; } c; c.f = f;
    const unsigned r = 0x7FFFu + ((c.u >> 16) & 1u);
    return (ushort)((c.u + r) >> 16);
}

// ---------------- Wc = W0 @ W1 @ W2 (single block) ----------------
__global__ __launch_bounds__(256) void k_wchain(const float* __restrict__ W0,
                                                const float* __restrict__ W1,
                                                const float* __restrict__ W2,
                                                float* __restrict__ Wc) {
    __shared__ float A[4096], B[4096], T[4096];
    const int t = threadIdx.x;
    for (int i = t; i < 1024; i += 256) {
        ((float4*)A)[i] = ((const float4*)W0)[i];
        ((float4*)B)[i] = ((const float4*)W1)[i];
    }
    __syncthreads();
#pragma unroll
    for (int g = 0; g < 4; ++g) {
        const int idx = t + 256 * g;
        const int r = idx >> 4, c4 = idx & 15;
        float4 acc = make_float4(0.f, 0.f, 0.f, 0.f);
#pragma unroll
        for (int k = 0; k < 64; ++k) {
            const float a = A[r * 64 + k];
            const float4 b = ((float4*)B)[k * 16 + c4];
            acc.x = fmaf(a, b.x, acc.x); acc.y = fmaf(a, b.y, acc.y);
            acc.z = fmaf(a, b.z, acc.z); acc.w = fmaf(a, b.w, acc.w);
        }
        ((float4*)T)[idx] = acc;
    }
    __syncthreads();
    for (int i = t; i < 1024; i += 256) ((float4*)B)[i] = ((const float4*)W2)[i];
    __syncthreads();
#pragma unroll
    for (int g = 0; g < 4; ++g) {
        const int idx = t + 256 * g;
        const int r = idx >> 4, c4 = idx & 15;
        float4 acc = make_float4(0.f, 0.f, 0.f, 0.f);
#pragma unroll
        for (int k = 0; k < 64; ++k) {
            const float a = T[r * 64 + k];
            const float4 b = ((float4*)B)[k * 16 + c4];
            acc.x = fmaf(a, b.x, acc.x); acc.y = fmaf(a, b.y, acc.y);
            acc.z = fmaf(a, b.z, acc.z); acc.w = fmaf(a, b.w, acc.w);
        }
        ((float4*)Wc)[idx] = acc;
    }
}

// ---------------- f32 -> bf16 convert (streaming) ----------------
__global__ __launch_bounds__(256) void k_tobf(const float* __restrict__ X,
                                              ushort* __restrict__ B, long long n4) {
    const long long stride = (long long)gridDim.x * 256;
    for (long long i = blockIdx.x * 256ll + threadIdx.x; i < n4; i += stride) {
        const float4 v = ((const float4*)X)[i];
        ushort4 u;
        u.x = f2bf(v.x); u.y = f2bf(v.y); u.z = f2bf(v.z); u.w = f2bf(v.w);
        ((ushort4*)B)[i] = u;
    }
}

// ---------------- A0: global segment histogram (LDS-aggregated) ----------------
__global__ __launch_bounds__(256) void k_a0(const int* __restrict__ ei,
                                            int* __restrict__ ghist, int E) {
    __shared__ int h[MAXSEG];
    const int t = threadIdx.x;
    for (int i = t; i < MAXSEG; i += 256) h[i] = 0;
    __syncthreads();
    for (int e = blockIdx.x * 256 + t; e < E; e += gridDim.x * 256)
        atomicAdd(&h[ei[E + e] >> SEGSHIFT], 1);
    __syncthreads();
    for (int i = t; i < MAXSEG; i += 256) {
        const int c = h[i];
        if (c) atomicAdd(&ghist[i], c);
    }
}

// ---------------- A-scan: gOff/gcur from ghist; also rp[N]=E ----------------
__global__ __launch_bounds__(MAXSEG) void k_ascan(const int* __restrict__ ghist,
                                                  int* __restrict__ gOff,
                                                  int* __restrict__ gcur,
                                                  int* __restrict__ rp, int N, int E) {
    __shared__ int sd[MAXSEG];
    const int t = threadIdx.x;
    const int v = ghist[t];
    sd[t] = v; __syncthreads();
    for (int off = 1; off < MAXSEG; off <<= 1) {
        const int y = (t >= off) ? sd[t - off] : 0;
        __syncthreads();
        sd[t] += y;
        __syncthreads();
    }
    const int excl = sd[t] - v;
    gOff[t] = excl; gcur[t] = excl;
    if (t == MAXSEG - 1) gOff[MAXSEG] = sd[t];
    if (t == 0) rp[N] = E;
}

// ---------------- A-partition: LDS counting sort -> per-segment pair runs ----
__global__ __launch_bounds__(512) void k_apart(const int* __restrict__ ei,
                                               int* __restrict__ gcur,
                                               uint2* __restrict__ ebuf, int E) {
    __shared__ int hist[MAXSEG], lofs[MAXSEG], cur[MAXSEG], gbase[MAXSEG];
    __shared__ uint2 stg[A_EPB];
    const int t = threadIdx.x;
    const int base = blockIdx.x * A_EPB;
    const int cnt = min(A_EPB, E - base);

    hist[t] = 0;                 // 512 threads == MAXSEG
    __syncthreads();

    uint2 my[8]; int mb[8];
#pragma unroll
    for (int j = 0; j < 8; ++j) {
        const int i = t + j * 512;
        if (i < cnt) {
            const int e = base + i;
            const int s = ei[e];
            const int d = ei[E + e];
            my[j] = make_uint2((unsigned)s, (unsigned)d);
            mb[j] = d >> SEGSHIFT;
            atomicAdd(&hist[mb[j]], 1);
        } else mb[j] = -1;
    }
    __syncthreads();

    // exclusive block scan of hist -> lofs (and cursor copy)
    {
        const int v = hist[t];
        lofs[t] = v; __syncthreads();
        for (int off = 1; off < MAXSEG; off <<= 1) {
            const int y = (t >= off) ? lofs[t - off] : 0;
            __syncthreads();
            lofs[t] += y;
            __syncthreads();
        }
        const int excl = lofs[t] - v;
        __syncthreads();
        lofs[t] = excl; cur[t] = excl;
    }
    __syncthreads();

    // place pairs into stg grouped by segment
#pragma unroll
    for (int j = 0; j < 8; ++j) {
        if (mb[j] >= 0) {
            const int p = atomicAdd(&cur[mb[j]], 1);
            stg[p] = my[j];
        }
    }
    __syncthreads();

    // reserve global space per segment (one hot atomic per nonempty segment)
    {
        const int c = hist[t];
        gbase[t] = c ? atomicAdd(&gcur[t], c) : 0;
    }
    __syncthreads();

    // copy runs out (consecutive i within a run -> coalesced global writes)
    for (int i = t; i < cnt; i += 512) {
        const uint2 pr = stg[i];
        const int b = (int)(pr.y >> SEGSHIFT);
        ebuf[(size_t)gbase[b] + (unsigned)(i - lofs[b])] = pr;
    }
}

// ---------------- B-place: per-segment counting sort -> rp + cs ----------------
__global__ __launch_bounds__(SEGROWS) void k_bplace(const uint2* __restrict__ ebuf,
                                                    const int* __restrict__ gOff,
                                                    int* __restrict__ rp,
                                                    int* __restrict__ cs, int N) {
    __shared__ int h[SEGROWS], ofs[SEGROWS];
    const int s = blockIdx.x;
    const int t = threadIdx.x;
    const int e0 = gOff[s];
    const int e1 = gOff[s + 1];

    h[t] = 0; __syncthreads();
    for (int e = e0 + t; e < e1; e += SEGROWS)
        atomicAdd(&h[ebuf[e].y & (SEGROWS - 1)], 1);
    __syncthreads();

    const int v = h[t];
    ofs[t] = v; __syncthreads();
    for (int off = 1; off < SEGROWS; off <<= 1) {
        const int y = (t >= off) ? ofs[t - off] : 0;
        __syncthreads();
        ofs[t] += y;
        __syncthreads();
    }
    const int excl = ofs[t] - v;
    const int r = s * SEGROWS + t;
    if (r < N) rp[r] = e0 + excl;
    __syncthreads();
    ofs[t] = excl;                 // becomes the within-segment cursor
    __syncthreads();

    for (int e = e0 + t; e < e1; e += SEGROWS) {
        const uint2 pr = ebuf[e];
        const int lr = (int)(pr.y & (SEGROWS - 1));
        const int p = atomicAdd(&ofs[lr], 1);
        cs[e0 + p] = (int)pr.x;
    }
}

// ---------------- Aggregation: out[r,:] = sum_{e in row r} B[cs[e],:] ----
__global__ __launch_bounds__(256) void k_aggc(const ushort* __restrict__ B,
                                              const int* __restrict__ rp,
                                              const int* __restrict__ cs,
                                              ushort* __restrict__ out, int N) {
    const int t = threadIdx.x;
    const int gw = (blockIdx.x * 256 + t) >> 6;
    const int lane = t & 63;
    const int q = lane >> 4;
    const int f4 = lane & 15;
    const int r = gw * 4 + q;
    if (r >= N) return;

    const int e0 = rp[r];
    const int e1 = rp[r + 1];
    const ushort4* Bv = (const ushort4*)B;

    float4 acc = make_float4(0.f, 0.f, 0.f, 0.f);
    int e = e0;
    for (; e + 3 < e1; e += 4) {
        const int s0 = cs[e], s1 = cs[e + 1], s2 = cs[e + 2], s3 = cs[e + 3];
        const ushort4 u0 = Bv[(size_t)s0 * 16 + f4];
        const ushort4 u1 = Bv[(size_t)s1 * 16 + f4];
        const ushort4 u2 = Bv[(size_t)s2 * 16 + f4];
        const ushort4 u3 = Bv[(size_t)s3 * 16 + f4];
        acc.x += bf2f(u0.x) + bf2f(u1.x) + bf2f(u2.x) + bf2f(u3.x);
        acc.y += bf2f(u0.y) + bf2f(u1.y) + bf2f(u2.y) + bf2f(u3.y);
        acc.z += bf2f(u0.z) + bf2f(u1.z) + bf2f(u2.z) + bf2f(u3.z);
        acc.w += bf2f(u0.w) + bf2f(u1.w) + bf2f(u2.w) + bf2f(u3.w);
    }
    for (; e < e1; ++e) {
        const ushort4 u = Bv[(size_t)cs[e] * 16 + f4];
        acc.x += bf2f(u.x); acc.y += bf2f(u.y);
        acc.z += bf2f(u.z); acc.w += bf2f(u.w);
    }
    ushort4 o;
    o.x = f2bf(acc.x); o.y = f2bf(acc.y); o.z = f2bf(acc.z); o.w = f2bf(acc.w);
    ((ushort4*)out)[(size_t)r * 16 + f4] = o;
}

// ---------------- GEMM (bf16 input): OUT[r,:] = X[r,:] @ W ----------------
__global__ __launch_bounds__(256) void gcn_gemm64b(const ushort* __restrict__ X,
                                                   const float* __restrict__ W,
                                                   float* __restrict__ H,
                                                   int nrows) {
    __shared__ float Wl[64 * 64];
    __shared__ float Xl[16][65];

    const int tid = threadIdx.x;
    for (int i = tid; i < 1024; i += 256) ((float4*)Wl)[i] = ((const float4*)W)[i];

    const int rowBase = blockIdx.x * 16;
    const int lr = tid >> 4;
    const int lc = tid & 15;
    const int grow = rowBase + lr;

    if (grow < nrows) {
        const ushort4 u = ((const ushort4*)X)[(size_t)grow * 16 + lc];
        Xl[lr][lc * 4 + 0] = bf2f(u.x);
        Xl[lr][lc * 4 + 1] = bf2f(u.y);
        Xl[lr][lc * 4 + 2] = bf2f(u.z);
        Xl[lr][lc * 4 + 3] = bf2f(u.w);
    }
    __syncthreads();

    float4 acc = make_float4(0.f, 0.f, 0.f, 0.f);
#pragma unroll
    for (int k = 0; k < 64; ++k) {
        const float xv = Xl[lr][k];
        const float4 w4 = ((const float4*)Wl)[k * 16 + lc];
        acc.x = fmaf(xv, w4.x, acc.x);
        acc.y = fmaf(xv, w4.y, acc.y);
        acc.z = fmaf(xv, w4.z, acc.z);
        acc.w = fmaf(xv, w4.w, acc.w);
    }
    if (grow < nrows) ((float4*)H)[(size_t)grow * 16 + lc] = acc;
}

// ---------------- R1 fallback kernels ----------------
__global__ __launch_bounds__(256) void gcn_gemm64(const float* __restrict__ X,
                                                  const float* __restrict__ W,
                                                  float* __restrict__ H,
                                                  int nrows) {
    __shared__ float Wl[64 * 64];
    __shared__ float Xl[16][65];
    const int tid = threadIdx.x;
    for (int i = tid; i < 1024; i += 256) ((float4*)Wl)[i] = ((const float4*)W)[i];
    const int rowBase = blockIdx.x * 16;
    const int lr = tid >> 4;
    const int lc = tid & 15;
    const int grow = rowBase + lr;
    if (grow < nrows) {
        float4 xv = ((const float4*)X)[(long long)grow * 16 + lc];
        Xl[lr][lc * 4 + 0] = xv.x; Xl[lr][lc * 4 + 1] = xv.y;
        Xl[lr][lc * 4 + 2] = xv.z; Xl[lr][lc * 4 + 3] = xv.w;
    }
    __syncthreads();
    float4 acc = make_float4(0.f, 0.f, 0.f, 0.f);
#pragma unroll
    for (int k = 0; k < 64; ++k) {
        const float xv = Xl[lr][k];
        const float4 w4 = ((const float4*)Wl)[k * 16 + lc];
        acc.x = fmaf(xv, w4.x, acc.x); acc.y = fmaf(xv, w4.y, acc.y);
        acc.z = fmaf(xv, w4.z, acc.z); acc.w = fmaf(xv, w4.w, acc.w);
    }
    if (grow < nrows) ((float4*)H)[(long long)grow * 16 + lc] = acc;
}

__global__ __launch_bounds__(256) void gcn_scatter(const float* __restrict__ H,
                                                   const int* __restrict__ ei,
                                                   float* __restrict__ out,
                                                   int nedges) {
    const long long t = (long long)blockIdx.x * 256 + threadIdx.x;
    const int e = (int)(t >> 4);
    if (e >= nedges) return;
    const int lc = (int)(t & 15);
    const int s = ei[e];
    const int d = ei[nedges + e];
    const float4 v = ((const float4*)H)[(long long)s * 16 + lc];
    float* o = out + (long long)d * GCN_D + lc * 4;
    atomicAdd(o + 0, v.x);
    atomicAdd(o + 1, v.y);
    atomicAdd(o + 2, v.z);
    atomicAdd(o + 3, v.w);
}

extern "C" void kernel_launch(void* const* d_in, const int* in_sizes, int n_in,
                              void* d_out, int out_size, void* d_ws, size_t ws_size,
                              hipStream_t stream) {
    const float* x  = (const float*)d_in[0];
    const int*   ei = (const int*)d_in[1];   // [2,E] flat: src then dst (int32)
    const float* W0 = (const float*)d_in[2];
    const float* W1 = (const float*)d_in[3];
    const float* W2 = (const float*)d_in[4];
    float* out = (float*)d_out;

    const int N_ = in_sizes[0] / GCN_D;
    const int E_ = in_sizes[1] / 2;
    const int NSEG = (N_ + SEGROWS - 1) >> SEGSHIFT;

    // ws layout:
    //   B0 (N*64 bf16) | REG (max(N*64 bf16, E*8) -- B1 and ebuf alias, disjoint
    //   lifetimes) | rp (N+1) | gOff (MAXSEG+1) | ghist (MAXSEG) | gcur (MAXSEG)
    //   | Wc (4096 f32) | cs (E int)
    uintptr_t base = (uintptr_t)d_ws;
    ushort* B0 = (ushort*)base;
    const size_t bfBytes  = (size_t)N_ * GCN_D * 2;
    const size_t regBytes = bfBytes > (size_t)E_ * 8 ? bfBytes : (size_t)E_ * 8;
    ushort* B1   = (ushort*)(base + bfBytes);
    uint2*  ebuf = (uint2*)B1;               // alias: dead before first k_aggc
    int* rp    = (int*)(base + bfBytes + regBytes);
    int* gOff  = rp + (N_ + 2);
    int* ghist = gOff + (MAXSEG + 1);
    int* gcur  = ghist + MAXSEG;
    float* Wc  = (float*)(gcur + MAXSEG);
    int* cs    = (int*)(Wc + 4096);
    const size_t needed = ((uintptr_t)(cs + E_) - base);

    const int gemmBlocks = (N_ + 15) / 16;

    if (NSEG <= MAXSEG && ws_size >= needed) {
        k_wchain<<<1, 256, 0, stream>>>(W0, W1, W2, Wc);
        k_tobf<<<1024, 256, 0, stream>>>(x, B0, (long long)N_ * 16);
        hipMemsetAsync(ghist, 0, MAXSEG * 4, stream);
        k_a0<<<512, 256, 0, stream>>>(ei, ghist, E_);
        k_ascan<<<1, MAXSEG, 0, stream>>>(ghist, gOff, gcur, rp, N_, E_);
        k_apart<<<(E_ + A_EPB - 1) / A_EPB, 512, 0, stream>>>(ei, gcur, ebuf, E_);
        k_bplace<<<NSEG, SEGROWS, 0, stream>>>(ebuf, gOff, rp, cs, N_);

        const int aggBlocks = (N_ + 15) / 16;     // 4 rows/wave, 4 waves/block
        k_aggc<<<aggBlocks, 256, 0, stream>>>(B0, rp, cs, B1, N_);   // a1
        k_aggc<<<aggBlocks, 256, 0, stream>>>(B1, rp, cs, B0, N_);   // a2
        k_aggc<<<aggBlocks, 256, 0, stream>>>(B0, rp, cs, B1, N_);   // a3
        gcn_gemm64b<<<gemmBlocks, 256, 0, stream>>>(B1, Wc, out, N_);
    } else {
        // Fallback: R1 path (needs only h = N*64 f32).
        float* h = (float*)d_ws;
        const int scatBlocks = (int)(((long long)E_ * 16 + 255) / 256);
        const int edgeBlocks = (E_ + 255) / 256;
        (void)edgeBlocks;
        const float* curAct = x;
        for (int l = 0; l < 3; ++l) {
            const float* Wl = (l == 0) ? W0 : (l == 1) ? W1 : W2;
            gcn_gemm64<<<gemmBlocks, 256, 0, stream>>>(curAct, Wl, h, N_);
            hipMemsetAsync(out, 0, (size_t)N_ * GCN_D * sizeof(float), stream);
            gcn_scatter<<<scatBlocks, 256, 0, stream>>>(h, ei, out, E_);
            curAct = out;
        }
    }
}

// Round 8
// 177.140 us; speedup vs baseline: 8.2685x; 1.0700x over previous
//
#include <hip/hip_runtime.h>

// 3-layer GCN on MI355X:  out = S^3(x) · (W0 W1 W2),  S = scatter-add over E edges.
// N = 100000, E = 1200000, D = 64.
//
// Per launch (no cross-call state):
//   k_wchain : Wc = W0 @ W1 @ W2                     (1 block)
//   k_tobf   : B0 = bf16(x); block 0 zeroes ghist
//   k_a0/k_ascan: 256-row segment histogram + scan   (LDS-aggregated)
//   k_apart  : LDS counting-sort blocks of 4096 edges -> packed (src<<8|lr)
//              words copied run-wise to per-segment cursors
//   k_bplace : per-segment LDS counting sort -> rp (CSR offsets) + cs (srcs)
//   k_aggc x2: stream cs, gather bf16 rows (8-deep), f32 accum, write bf16
//   k_aggf   : 3rd aggregation with fused GEMM -> f32 d_out

#define GCN_D 64
#define SEGSHIFT 8
#define SEGROWS 256          // dst rows per segment
#define MAXSEG 512           // compile-time LDS capacity (N <= 131072)
#define A_EPB 4096           // edges per k_apart block

typedef unsigned short ushort;

__device__ __forceinline__ float bf2f(ushort u) {
    union { unsigned u; float f; } c; c.u = ((unsigned)u) << 16; return c.f;
}
// RNE f32 -> bf16 (finite inputs): add 0x7FFF + lsb(bit16), truncate.
__device__ __forceinline__ ushort f2bf(float f) {
    union { float f; unsigned u; } c; c.f = f;
    const unsigned r = 0x7FFFu + ((c.u >> 16) & 1u);
    return (ushort)((c.u + r) >> 16);
}

// ---------------- Wc = W0 @ W1 @ W2 (single block) ----------------
__global__ __launch_bounds__(256) void k_wchain(const float* __restrict__ W0,
                                                const float* __restrict__ W1,
                                                const float* __restrict__ W2,
                                                float* __restrict__ Wc) {
    __shared__ float A[4096], B[4096], T[4096];
    const int t = threadIdx.x;
    for (int i = t; i < 1024; i += 256) {
        ((float4*)A)[i] = ((const float4*)W0)[i];
        ((float4*)B)[i] = ((const float4*)W1)[i];
    }
    __syncthreads();
#pragma unroll
    for (int g = 0; g < 4; ++g) {
        const int idx = t + 256 * g;
        const int r = idx >> 4, c4 = idx & 15;
        float4 acc = make_float4(0.f, 0.f, 0.f, 0.f);
#pragma unroll
        for (int k = 0; k < 64; ++k) {
            const float a = A[r * 64 + k];
            const float4 b = ((float4*)B)[k * 16 + c4];
            acc.x = fmaf(a, b.x, acc.x); acc.y = fmaf(a, b.y, acc.y);
            acc.z = fmaf(a, b.z, acc.z); acc.w = fmaf(a, b.w, acc.w);
        }
        ((float4*)T)[idx] = acc;
    }
    __syncthreads();
    for (int i = t; i < 1024; i += 256) ((float4*)B)[i] = ((const float4*)W2)[i];
    __syncthreads();
#pragma unroll
    for (int g = 0; g < 4; ++g) {
        const int idx = t + 256 * g;
        const int r = idx >> 4, c4 = idx & 15;
        float4 acc = make_float4(0.f, 0.f, 0.f, 0.f);
#pragma unroll
        for (int k = 0; k < 64; ++k) {
            const float a = T[r * 64 + k];
            const float4 b = ((float4*)B)[k * 16 + c4];
            acc.x = fmaf(a, b.x, acc.x); acc.y = fmaf(a, b.y, acc.y);
            acc.z = fmaf(a, b.z, acc.z); acc.w = fmaf(a, b.w, acc.w);
        }
        ((float4*)Wc)[idx] = acc;
    }
}

// ---------------- f32 -> bf16 convert (streaming); block 0 zeroes ghist ------
__global__ __launch_bounds__(256) void k_tobf(const float* __restrict__ X,
                                              ushort* __restrict__ B,
                                              int* __restrict__ ghist, long long n4) {
    if (blockIdx.x == 0) {
        for (int i = threadIdx.x; i < MAXSEG; i += 256) ghist[i] = 0;
    }
    const long long stride = (long long)gridDim.x * 256;
    for (long long i = blockIdx.x * 256ll + threadIdx.x; i < n4; i += stride) {
        const float4 v = ((const float4*)X)[i];
        ushort4 u;
        u.x = f2bf(v.x); u.y = f2bf(v.y); u.z = f2bf(v.z); u.w = f2bf(v.w);
        ((ushort4*)B)[i] = u;
    }
}

// ---------------- A0: global segment histogram (LDS-aggregated) ----------------
__global__ __launch_bounds__(256) void k_a0(const int* __restrict__ ei,
                                            int* __restrict__ ghist, int E) {
    __shared__ int h[MAXSEG];
    const int t = threadIdx.x;
    for (int i = t; i < MAXSEG; i += 256) h[i] = 0;
    __syncthreads();
    for (int e = blockIdx.x * 256 + t; e < E; e += gridDim.x * 256)
        atomicAdd(&h[ei[E + e] >> SEGSHIFT], 1);
    __syncthreads();
    for (int i = t; i < MAXSEG; i += 256) {
        const int c = h[i];
        if (c) atomicAdd(&ghist[i], c);
    }
}

// ---------------- A-scan: gOff/gcur from ghist; also rp[N]=E ----------------
__global__ __launch_bounds__(MAXSEG) void k_ascan(const int* __restrict__ ghist,
                                                  int* __restrict__ gOff,
                                                  int* __restrict__ gcur,
                                                  int* __restrict__ rp, int N, int E) {
    __shared__ int sd[MAXSEG];
    const int t = threadIdx.x;
    const int v = ghist[t];
    sd[t] = v; __syncthreads();
    for (int off = 1; off < MAXSEG; off <<= 1) {
        const int y = (t >= off) ? sd[t - off] : 0;
        __syncthreads();
        sd[t] += y;
        __syncthreads();
    }
    const int excl = sd[t] - v;
    gOff[t] = excl; gcur[t] = excl;
    if (t == MAXSEG - 1) gOff[MAXSEG] = sd[t];
    if (t == 0) rp[N] = E;
}

// ---------------- A-partition: LDS counting sort -> packed per-segment runs --
// Packed word: (src << 8) | (dst & 255). src < 2^24 required.
__global__ __launch_bounds__(512) void k_apart(const int* __restrict__ ei,
                                               int* __restrict__ gcur,
                                               unsigned* __restrict__ ebuf, int E) {
    __shared__ int hist[MAXSEG], lofs[MAXSEG], cur[MAXSEG], gbase[MAXSEG];
    __shared__ unsigned stg[A_EPB];
    const int t = threadIdx.x;
    const int base = blockIdx.x * A_EPB;
    const int cnt = min(A_EPB, E - base);

    hist[t] = 0;                 // 512 threads == MAXSEG
    __syncthreads();

    unsigned my[8]; int mb[8];
#pragma unroll
    for (int j = 0; j < 8; ++j) {
        const int i = t + j * 512;
        if (i < cnt) {
            const int e = base + i;
            const unsigned s = (unsigned)ei[e];
            const unsigned d = (unsigned)ei[E + e];
            my[j] = (s << 8) | (d & (SEGROWS - 1));
            mb[j] = (int)(d >> SEGSHIFT);
            atomicAdd(&hist[mb[j]], 1);
        } else mb[j] = -1;
    }
    __syncthreads();

    // exclusive block scan of hist -> lofs (and cursor copy)
    {
        const int v = hist[t];
        lofs[t] = v; __syncthreads();
        for (int off = 1; off < MAXSEG; off <<= 1) {
            const int y = (t >= off) ? lofs[t - off] : 0;
            __syncthreads();
            lofs[t] += y;
            __syncthreads();
        }
        const int excl = lofs[t] - v;
        __syncthreads();
        lofs[t] = excl; cur[t] = excl;
    }
    __syncthreads();

    // place packed words into stg grouped by segment
#pragma unroll
    for (int j = 0; j < 8; ++j) {
        if (mb[j] >= 0) {
            const int p = atomicAdd(&cur[mb[j]], 1);
            stg[p] = my[j];
        }
    }
    __syncthreads();

    // reserve global space per segment (one hot atomic per nonempty segment)
    {
        const int c = hist[t];
        gbase[t] = c ? atomicAdd(&gcur[t], c) : 0;
    }
    __syncthreads();

    // copy runs out; recover segment of slot i by binary search over lofs
    for (int i = t; i < cnt; i += 512) {
        int lo = 0, hi = MAXSEG - 1;
        while (lo < hi) {
            const int mid = (lo + hi + 1) >> 1;
            if (lofs[mid] <= i) lo = mid; else hi = mid - 1;
        }
        ebuf[(size_t)gbase[lo] + (unsigned)(i - lofs[lo])] = stg[i];
    }
}

// ---------------- B-place: per-segment counting sort -> rp + cs ----------------
__global__ __launch_bounds__(SEGROWS) void k_bplace(const unsigned* __restrict__ ebuf,
                                                    const int* __restrict__ gOff,
                                                    int* __restrict__ rp,
                                                    int* __restrict__ cs, int N) {
    __shared__ int h[SEGROWS], ofs[SEGROWS];
    const int s = blockIdx.x;
    const int t = threadIdx.x;
    const int e0 = gOff[s];
    const int e1 = gOff[s + 1];

    h[t] = 0; __syncthreads();
    for (int e = e0 + t; e < e1; e += SEGROWS)
        atomicAdd(&h[ebuf[e] & (SEGROWS - 1)], 1);
    __syncthreads();

    const int v = h[t];
    ofs[t] = v; __syncthreads();
    for (int off = 1; off < SEGROWS; off <<= 1) {
        const int y = (t >= off) ? ofs[t - off] : 0;
        __syncthreads();
        ofs[t] += y;
        __syncthreads();
    }
    const int excl = ofs[t] - v;
    const int r = s * SEGROWS + t;
    if (r < N) rp[r] = e0 + excl;
    __syncthreads();
    ofs[t] = excl;                 // becomes the within-segment cursor
    __syncthreads();

    for (int e = e0 + t; e < e1; e += SEGROWS) {
        const unsigned pr = ebuf[e];
        const int lr = (int)(pr & (SEGROWS - 1));
        const int p = atomicAdd(&ofs[lr], 1);
        cs[e0 + p] = (int)(pr >> 8);
    }
}

// ---------------- Aggregation: out[r,:] = sum_{e in row r} B[cs[e],:] ----
// 1 wave = 4 rows (16-lane quarter each); 8-deep unroll -> 32 gathers in
// flight per wave. f32 accumulate, bf16 RNE write.
__global__ __launch_bounds__(256) void k_aggc(const ushort* __restrict__ B,
                                              const int* __restrict__ rp,
                                              const int* __restrict__ cs,
                                              ushort* __restrict__ out, int N) {
    const int t = threadIdx.x;
    const int gw = (blockIdx.x * 256 + t) >> 6;
    const int lane = t & 63;
    const int f4 = lane & 15;
    const int r = gw * 4 + (lane >> 4);
    if (r >= N) return;

    const int e0 = rp[r];
    const int e1 = rp[r + 1];
    const ushort4* Bv = (const ushort4*)B;

    float4 acc = make_float4(0.f, 0.f, 0.f, 0.f);
    int e = e0;
    for (; e + 7 < e1; e += 8) {
        ushort4 u[8];
#pragma unroll
        for (int j = 0; j < 8; ++j) u[j] = Bv[(size_t)cs[e + j] * 16 + f4];
#pragma unroll
        for (int j = 0; j < 8; ++j) {
            acc.x += bf2f(u[j].x); acc.y += bf2f(u[j].y);
            acc.z += bf2f(u[j].z); acc.w += bf2f(u[j].w);
        }
    }
    for (; e + 3 < e1; e += 4) {
        ushort4 u[4];
#pragma unroll
        for (int j = 0; j < 4; ++j) u[j] = Bv[(size_t)cs[e + j] * 16 + f4];
#pragma unroll
        for (int j = 0; j < 4; ++j) {
            acc.x += bf2f(u[j].x); acc.y += bf2f(u[j].y);
            acc.z += bf2f(u[j].z); acc.w += bf2f(u[j].w);
        }
    }
    for (; e < e1; ++e) {
        const ushort4 u = Bv[(size_t)cs[e] * 16 + f4];
        acc.x += bf2f(u.x); acc.y += bf2f(u.y);
        acc.z += bf2f(u.z); acc.w += bf2f(u.w);
    }
    ushort4 o;
    o.x = f2bf(acc.x); o.y = f2bf(acc.y); o.z = f2bf(acc.z); o.w = f2bf(acc.w);
    ((ushort4*)out)[(size_t)r * 16 + f4] = o;
}

// ---------------- Aggregation + fused GEMM: out = (S a2) @ Wc (f32) ----------
// Block = 256 thr = 16 rows. Agg as in k_aggc, rows staged through LDS,
// then the 16-row GEMM against LDS-resident Wc.
__global__ __launch_bounds__(256) void k_aggf(const ushort* __restrict__ B,
                                              const int* __restrict__ rp,
                                              const int* __restrict__ cs,
                                              const float* __restrict__ Wc,
                                              float* __restrict__ out, int N) {
    __shared__ float Wl[64 * 64];
    __shared__ float Xl[16][65];
    const int t = threadIdx.x;
    for (int i = t; i < 1024; i += 256) ((float4*)Wl)[i] = ((const float4*)Wc)[i];

    const int lr = t >> 4;                    // local row 0..15
    const int f4 = t & 15;
    const int r = blockIdx.x * 16 + lr;

    float4 acc = make_float4(0.f, 0.f, 0.f, 0.f);
    if (r < N) {
        const int e0 = rp[r];
        const int e1 = rp[r + 1];
        const ushort4* Bv = (const ushort4*)B;
        int e = e0;
        for (; e + 7 < e1; e += 8) {
            ushort4 u[8];
#pragma unroll
            for (int j = 0; j < 8; ++j) u[j] = Bv[(size_t)cs[e + j] * 16 + f4];
#pragma unroll
            for (int j = 0; j < 8; ++j) {
                acc.x += bf2f(u[j].x); acc.y += bf2f(u[j].y);
                acc.z += bf2f(u[j].z); acc.w += bf2f(u[j].w);
            }
        }
        for (; e + 3 < e1; e += 4) {
            ushort4 u[4];
#pragma unroll
            for (int j = 0; j < 4; ++j) u[j] = Bv[(size_t)cs[e + j] * 16 + f4];
#pragma unroll
            for (int j = 0; j < 4; ++j) {
                acc.x += bf2f(u[j].x); acc.y += bf2f(u[j].y);
                acc.z += bf2f(u[j].z); acc.w += bf2f(u[j].w);
            }
        }
        for (; e < e1; ++e) {
            const ushort4 u = Bv[(size_t)cs[e] * 16 + f4];
            acc.x += bf2f(u.x); acc.y += bf2f(u.y);
            acc.z += bf2f(u.z); acc.w += bf2f(u.w);
        }
    }
    // bf16-round the aggregated row to match the unfused path's numerics
    Xl[lr][f4 * 4 + 0] = bf2f(f2bf(acc.x));
    Xl[lr][f4 * 4 + 1] = bf2f(f2bf(acc.y));
    Xl[lr][f4 * 4 + 2] = bf2f(f2bf(acc.z));
    Xl[lr][f4 * 4 + 3] = bf2f(f2bf(acc.w));
    __syncthreads();

    float4 g = make_float4(0.f, 0.f, 0.f, 0.f);
#pragma unroll
    for (int k = 0; k < 64; ++k) {
        const float xv = Xl[lr][k];
        const float4 w4 = ((const float4*)Wl)[k * 16 + f4];
        g.x = fmaf(xv, w4.x, g.x); g.y = fmaf(xv, w4.y, g.y);
        g.z = fmaf(xv, w4.z, g.z); g.w = fmaf(xv, w4.w, g.w);
    }
    if (r < N) ((float4*)out)[(size_t)r * 16 + f4] = g;
}

// ---------------- R1 fallback kernels ----------------
__global__ __launch_bounds__(256) void gcn_gemm64(const float* __restrict__ X,
                                                  const float* __restrict__ W,
                                                  float* __restrict__ H,
                                                  int nrows) {
    __shared__ float Wl[64 * 64];
    __shared__ float Xl[16][65];
    const int tid = threadIdx.x;
    for (int i = tid; i < 1024; i += 256) ((float4*)Wl)[i] = ((const float4*)W)[i];
    const int rowBase = blockIdx.x * 16;
    const int lr = tid >> 4;
    const int lc = tid & 15;
    const int grow = rowBase + lr;
    if (grow < nrows) {
        float4 xv = ((const float4*)X)[(long long)grow * 16 + lc];
        Xl[lr][lc * 4 + 0] = xv.x; Xl[lr][lc * 4 + 1] = xv.y;
        Xl[lr][lc * 4 + 2] = xv.z; Xl[lr][lc * 4 + 3] = xv.w;
    }
    __syncthreads();
    float4 acc = make_float4(0.f, 0.f, 0.f, 0.f);
#pragma unroll
    for (int k = 0; k < 64; ++k) {
        const float xv = Xl[lr][k];
        const float4 w4 = ((float4*)Wl)[k * 16 + lc];
        acc.x = fmaf(xv, w4.x, acc.x); acc.y = fmaf(xv, w4.y, acc.y);
        acc.z = fmaf(xv, w4.z, acc.z); acc.w = fmaf(xv, w4.w, acc.w);
    }
    if (grow < nrows) ((float4*)H)[(long long)grow * 16 + lc] = acc;
}

__global__ __launch_bounds__(256) void gcn_scatter(const float* __restrict__ H,
                                                   const int* __restrict__ ei,
                                                   float* __restrict__ out,
                                                   int nedges) {
    const long long t = (long long)blockIdx.x * 256 + threadIdx.x;
    const int e = (int)(t >> 4);
    if (e >= nedges) return;
    const int lc = (int)(t & 15);
    const int s = ei[e];
    const int d = ei[nedges + e];
    const float4 v = ((const float4*)H)[(long long)s * 16 + lc];
    float* o = out + (long long)d * GCN_D + lc * 4;
    atomicAdd(o + 0, v.x);
    atomicAdd(o + 1, v.y);
    atomicAdd(o + 2, v.z);
    atomicAdd(o + 3, v.w);
}

extern "C" void kernel_launch(void* const* d_in, const int* in_sizes, int n_in,
                              void* d_out, int out_size, void* d_ws, size_t ws_size,
                              hipStream_t stream) {
    const float* x  = (const float*)d_in[0];
    const int*   ei = (const int*)d_in[1];   // [2,E] flat: src then dst (int32)
    const float* W0 = (const float*)d_in[2];
    const float* W1 = (const float*)d_in[3];
    const float* W2 = (const float*)d_in[4];
    float* out = (float*)d_out;

    const int N_ = in_sizes[0] / GCN_D;
    const int E_ = in_sizes[1] / 2;
    const int NSEG = (N_ + SEGROWS - 1) >> SEGSHIFT;

    // ws layout:
    //   B0 (N*64 bf16) | REG (max(N*64 bf16, E*4) -- B1 and ebuf alias, disjoint
    //   lifetimes) | rp (N+2) | gOff (MAXSEG+1) | ghist (MAXSEG) | gcur (MAXSEG)
    //   | Wc (4096 f32) | cs (E int)
    uintptr_t base = (uintptr_t)d_ws;
    ushort* B0 = (ushort*)base;
    const size_t bfBytes  = (size_t)N_ * GCN_D * 2;
    const size_t regBytes = bfBytes > (size_t)E_ * 4 ? bfBytes : (size_t)E_ * 4;
    ushort*   B1   = (ushort*)(base + bfBytes);
    unsigned* ebuf = (unsigned*)B1;          // alias: dead before first k_aggc
    int* rp    = (int*)(base + bfBytes + regBytes);
    int* gOff  = rp + (N_ + 2);
    int* ghist = gOff + (MAXSEG + 1);
    int* gcur  = ghist + MAXSEG;
    float* Wc  = (float*)(gcur + MAXSEG);
    int* cs    = (int*)(Wc + 4096);
    const size_t needed = ((uintptr_t)(cs + E_) - base);

    const int gemmBlocks = (N_ + 15) / 16;

    if (NSEG <= MAXSEG && N_ < (1 << 24) && ws_size >= needed) {
        k_wchain<<<1, 256, 0, stream>>>(W0, W1, W2, Wc);
        k_tobf<<<1024, 256, 0, stream>>>(x, B0, ghist, (long long)N_ * 16);
        k_a0<<<512, 256, 0, stream>>>(ei, ghist, E_);
        k_ascan<<<1, MAXSEG, 0, stream>>>(ghist, gOff, gcur, rp, N_, E_);
        k_apart<<<(E_ + A_EPB - 1) / A_EPB, 512, 0, stream>>>(ei, gcur, ebuf, E_);
        k_bplace<<<NSEG, SEGROWS, 0, stream>>>(ebuf, gOff, rp, cs, N_);

        const int aggBlocks = (N_ + 15) / 16;     // 4 rows/wave, 4 waves/block
        k_aggc<<<aggBlocks, 256, 0, stream>>>(B0, rp, cs, B1, N_);        // a1
        k_aggc<<<aggBlocks, 256, 0, stream>>>(B1, rp, cs, B0, N_);        // a2
        k_aggf<<<aggBlocks, 256, 0, stream>>>(B0, rp, cs, Wc, out, N_);   // a3·Wc
    } else {
        // Fallback: R1 path (needs only h = N*64 f32).
        float* h = (float*)d_ws;
        const int scatBlocks = (int)(((long long)E_ * 16 + 255) / 256);
        const float* curAct = x;
        for (int l = 0; l < 3; ++l) {
            const float* Wl = (l == 0) ? W0 : (l == 1) ? W1 : W2;
            gcn_gemm64<<<gemmBlocks, 256, 0, stream>>>(curAct, Wl, h, N_);
            hipMemsetAsync(out, 0, (size_t)N_ * GCN_D * sizeof(float), stream);
            gcn_scatter<<<scatBlocks, 256, 0, stream>>>(h, ei, out, E_);
            curAct = out;
        }
    }
}

// Round 9
// 172.357 us; speedup vs baseline: 8.4980x; 1.0278x over previous
//
#include <hip/hip_runtime.h>

// 3-layer GCN on MI355X:  out = S^3(x · (W0 W1 W2)),  S = scatter-add over E edges.
// N = 100000, E = 1200000, D = 64.
//
// Per launch (no cross-call state):
//   k_wchain : Wc = W0 @ W1 @ W2; zero ghist          (1 block)
//   k_gemmcvt: B0 = bf16(x @ Wc)                      (GEMM applied FIRST)
//   k_a0/k_ascan: 256-row segment histogram + scan    (LDS-aggregated)
//   k_apart  : LDS counting-sort blocks of 4096 edges -> packed (src<<8|lr)
//              words copied run-wise to per-segment cursors (seg id staged)
//   k_bplace : per-segment LDS counting sort -> rp (CSR offsets) + cs (srcs)
//   k_aggc x2: stream cs, gather bf16 rows (8-deep), f32 accum, write bf16
//   k_aggw   : 3rd aggregation, writes f32 d_out directly

#define GCN_D 64
#define SEGSHIFT 8
#define SEGROWS 256          // dst rows per segment
#define MAXSEG 512           // compile-time LDS capacity (N <= 131072)
#define A_EPB 4096           // edges per k_apart block

typedef unsigned short ushort;

__device__ __forceinline__ float bf2f(ushort u) {
    union { unsigned u; float f; } c; c.u = ((unsigned)u) << 16; return c.f;
}
// RNE f32 -> bf16 (finite inputs): add 0x7FFF + lsb(bit16), truncate.
__device__ __forceinline__ ushort f2bf(float f) {
    union { float f; unsigned u; } c; c.f = f;
    const unsigned r = 0x7FFFu + ((c.u >> 16) & 1u);
    return (ushort)((c.u + r) >> 16);
}

// ---------------- Wc = W0 @ W1 @ W2 (single block); zero ghist ----------------
__global__ __launch_bounds__(256) void k_wchain(const float* __restrict__ W0,
                                                const float* __restrict__ W1,
                                                const float* __restrict__ W2,
                                                float* __restrict__ Wc,
                                                int* __restrict__ ghist) {
    __shared__ float A[4096], B[4096], T[4096];
    const int t = threadIdx.x;
    for (int i = t; i < MAXSEG; i += 256) ghist[i] = 0;
    for (int i = t; i < 1024; i += 256) {
        ((float4*)A)[i] = ((const float4*)W0)[i];
        ((float4*)B)[i] = ((const float4*)W1)[i];
    }
    __syncthreads();
#pragma unroll
    for (int g = 0; g < 4; ++g) {
        const int idx = t + 256 * g;
        const int r = idx >> 4, c4 = idx & 15;
        float4 acc = make_float4(0.f, 0.f, 0.f, 0.f);
#pragma unroll
        for (int k = 0; k < 64; ++k) {
            const float a = A[r * 64 + k];
            const float4 b = ((float4*)B)[k * 16 + c4];
            acc.x = fmaf(a, b.x, acc.x); acc.y = fmaf(a, b.y, acc.y);
            acc.z = fmaf(a, b.z, acc.z); acc.w = fmaf(a, b.w, acc.w);
        }
        ((float4*)T)[idx] = acc;
    }
    __syncthreads();
    for (int i = t; i < 1024; i += 256) ((float4*)B)[i] = ((const float4*)W2)[i];
    __syncthreads();
#pragma unroll
    for (int g = 0; g < 4; ++g) {
        const int idx = t + 256 * g;
        const int r = idx >> 4, c4 = idx & 15;
        float4 acc = make_float4(0.f, 0.f, 0.f, 0.f);
#pragma unroll
        for (int k = 0; k < 64; ++k) {
            const float a = T[r * 64 + k];
            const float4 b = ((float4*)B)[k * 16 + c4];
            acc.x = fmaf(a, b.x, acc.x); acc.y = fmaf(a, b.y, acc.y);
            acc.z = fmaf(a, b.z, acc.z); acc.w = fmaf(a, b.w, acc.w);
        }
        ((float4*)Wc)[idx] = acc;
    }
}

// ---------------- GEMM + convert: B[r,:] = bf16(X[r,:] @ Wc) ----------------
__global__ __launch_bounds__(256) void k_gemmcvt(const float* __restrict__ X,
                                                 const float* __restrict__ Wc,
                                                 ushort* __restrict__ B,
                                                 int nrows) {
    __shared__ float Wl[64 * 64];
    __shared__ float Xl[16][65];
    const int tid = threadIdx.x;
    for (int i = tid; i < 1024; i += 256) ((float4*)Wl)[i] = ((const float4*)Wc)[i];

    const int lr = tid >> 4;
    const int lc = tid & 15;
    const int grow = blockIdx.x * 16 + lr;

    if (grow < nrows) {
        const float4 xv = ((const float4*)X)[(size_t)grow * 16 + lc];
        Xl[lr][lc * 4 + 0] = xv.x; Xl[lr][lc * 4 + 1] = xv.y;
        Xl[lr][lc * 4 + 2] = xv.z; Xl[lr][lc * 4 + 3] = xv.w;
    }
    __syncthreads();

    float4 acc = make_float4(0.f, 0.f, 0.f, 0.f);
#pragma unroll
    for (int k = 0; k < 64; ++k) {
        const float xv = Xl[lr][k];
        const float4 w4 = ((const float4*)Wl)[k * 16 + lc];
        acc.x = fmaf(xv, w4.x, acc.x); acc.y = fmaf(xv, w4.y, acc.y);
        acc.z = fmaf(xv, w4.z, acc.z); acc.w = fmaf(xv, w4.w, acc.w);
    }
    if (grow < nrows) {
        ushort4 o;
        o.x = f2bf(acc.x); o.y = f2bf(acc.y); o.z = f2bf(acc.z); o.w = f2bf(acc.w);
        ((ushort4*)B)[(size_t)grow * 16 + lc] = o;
    }
}

// ---------------- A0: global segment histogram (LDS-aggregated) ----------------
__global__ __launch_bounds__(256) void k_a0(const int* __restrict__ ei,
                                            int* __restrict__ ghist, int E) {
    __shared__ int h[MAXSEG];
    const int t = threadIdx.x;
    for (int i = t; i < MAXSEG; i += 256) h[i] = 0;
    __syncthreads();
    for (int e = blockIdx.x * 256 + t; e < E; e += gridDim.x * 256)
        atomicAdd(&h[ei[E + e] >> SEGSHIFT], 1);
    __syncthreads();
    for (int i = t; i < MAXSEG; i += 256) {
        const int c = h[i];
        if (c) atomicAdd(&ghist[i], c);
    }
}

// ---------------- A-scan: gOff/gcur from ghist; also rp[N]=E ----------------
__global__ __launch_bounds__(MAXSEG) void k_ascan(const int* __restrict__ ghist,
                                                  int* __restrict__ gOff,
                                                  int* __restrict__ gcur,
                                                  int* __restrict__ rp, int N, int E) {
    __shared__ int sd[MAXSEG];
    const int t = threadIdx.x;
    const int v = ghist[t];
    sd[t] = v; __syncthreads();
    for (int off = 1; off < MAXSEG; off <<= 1) {
        const int y = (t >= off) ? sd[t - off] : 0;
        __syncthreads();
        sd[t] += y;
        __syncthreads();
    }
    const int excl = sd[t] - v;
    gOff[t] = excl; gcur[t] = excl;
    if (t == MAXSEG - 1) gOff[MAXSEG] = sd[t];
    if (t == 0) rp[N] = E;
}

// ---------------- A-partition: LDS counting sort -> packed per-segment runs --
// Packed word: (src << 8) | (dst & 255). src < 2^24 required.
__global__ __launch_bounds__(512) void k_apart(const int* __restrict__ ei,
                                               int* __restrict__ gcur,
                                               unsigned* __restrict__ ebuf, int E) {
    __shared__ int hist[MAXSEG], lofs[MAXSEG], cur[MAXSEG], gbase[MAXSEG];
    __shared__ unsigned stg[A_EPB];
    __shared__ ushort stg2[A_EPB];           // segment id per staged slot
    const int t = threadIdx.x;
    const int base = blockIdx.x * A_EPB;
    const int cnt = min(A_EPB, E - base);

    hist[t] = 0;                 // 512 threads == MAXSEG
    __syncthreads();

    unsigned my[8]; int mb[8];
#pragma unroll
    for (int j = 0; j < 8; ++j) {
        const int i = t + j * 512;
        if (i < cnt) {
            const int e = base + i;
            const unsigned s = (unsigned)ei[e];
            const unsigned d = (unsigned)ei[E + e];
            my[j] = (s << 8) | (d & (SEGROWS - 1));
            mb[j] = (int)(d >> SEGSHIFT);
            atomicAdd(&hist[mb[j]], 1);
        } else mb[j] = -1;
    }
    __syncthreads();

    // exclusive block scan of hist -> lofs (and cursor copy)
    {
        const int v = hist[t];
        lofs[t] = v; __syncthreads();
        for (int off = 1; off < MAXSEG; off <<= 1) {
            const int y = (t >= off) ? lofs[t - off] : 0;
            __syncthreads();
            lofs[t] += y;
            __syncthreads();
        }
        const int excl = lofs[t] - v;
        __syncthreads();
        lofs[t] = excl; cur[t] = excl;
    }
    __syncthreads();

    // place packed words into stg grouped by segment; remember segment id
#pragma unroll
    for (int j = 0; j < 8; ++j) {
        if (mb[j] >= 0) {
            const int p = atomicAdd(&cur[mb[j]], 1);
            stg[p] = my[j];
            stg2[p] = (ushort)mb[j];
        }
    }
    __syncthreads();

    // reserve global space per segment (one hot atomic per nonempty segment)
    {
        const int c = hist[t];
        gbase[t] = c ? atomicAdd(&gcur[t], c) : 0;
    }
    __syncthreads();

    // copy runs out (consecutive i within a run -> coalesced global writes)
    for (int i = t; i < cnt; i += 512) {
        const int b = (int)stg2[i];
        ebuf[(size_t)gbase[b] + (unsigned)(i - lofs[b])] = stg[i];
    }
}

// ---------------- B-place: per-segment counting sort -> rp + cs ----------------
__global__ __launch_bounds__(SEGROWS) void k_bplace(const unsigned* __restrict__ ebuf,
                                                    const int* __restrict__ gOff,
                                                    int* __restrict__ rp,
                                                    int* __restrict__ cs, int N) {
    __shared__ int h[SEGROWS], ofs[SEGROWS];
    const int s = blockIdx.x;
    const int t = threadIdx.x;
    const int e0 = gOff[s];
    const int e1 = gOff[s + 1];

    h[t] = 0; __syncthreads();
    for (int e = e0 + t; e < e1; e += SEGROWS)
        atomicAdd(&h[ebuf[e] & (SEGROWS - 1)], 1);
    __syncthreads();

    const int v = h[t];
    ofs[t] = v; __syncthreads();
    for (int off = 1; off < SEGROWS; off <<= 1) {
        const int y = (t >= off) ? ofs[t - off] : 0;
        __syncthreads();
        ofs[t] += y;
        __syncthreads();
    }
    const int excl = ofs[t] - v;
    const int r = s * SEGROWS + t;
    if (r < N) rp[r] = e0 + excl;
    __syncthreads();
    ofs[t] = excl;                 // becomes the within-segment cursor
    __syncthreads();

    for (int e = e0 + t; e < e1; e += SEGROWS) {
        const unsigned pr = ebuf[e];
        const int lr = (int)(pr & (SEGROWS - 1));
        const int p = atomicAdd(&ofs[lr], 1);
        cs[e0 + p] = (int)(pr >> 8);
    }
}

// ---------------- Aggregation: out[r,:] = sum_{e in row r} B[cs[e],:] ----
// 1 wave = 4 rows (16-lane quarter each); 8-deep unroll -> 32 gathers in
// flight per wave. f32 accumulate, bf16 RNE write.
__global__ __launch_bounds__(256) void k_aggc(const ushort* __restrict__ B,
                                              const int* __restrict__ rp,
                                              const int* __restrict__ cs,
                                              ushort* __restrict__ out, int N) {
    const int t = threadIdx.x;
    const int gw = (blockIdx.x * 256 + t) >> 6;
    const int lane = t & 63;
    const int f4 = lane & 15;
    const int r = gw * 4 + (lane >> 4);
    if (r >= N) return;

    const int e0 = rp[r];
    const int e1 = rp[r + 1];
    const ushort4* Bv = (const ushort4*)B;

    float4 acc = make_float4(0.f, 0.f, 0.f, 0.f);
    int e = e0;
    for (; e + 7 < e1; e += 8) {
        ushort4 u[8];
#pragma unroll
        for (int j = 0; j < 8; ++j) u[j] = Bv[(size_t)cs[e + j] * 16 + f4];
#pragma unroll
        for (int j = 0; j < 8; ++j) {
            acc.x += bf2f(u[j].x); acc.y += bf2f(u[j].y);
            acc.z += bf2f(u[j].z); acc.w += bf2f(u[j].w);
        }
    }
    for (; e + 3 < e1; e += 4) {
        ushort4 u[4];
#pragma unroll
        for (int j = 0; j < 4; ++j) u[j] = Bv[(size_t)cs[e + j] * 16 + f4];
#pragma unroll
        for (int j = 0; j < 4; ++j) {
            acc.x += bf2f(u[j].x); acc.y += bf2f(u[j].y);
            acc.z += bf2f(u[j].z); acc.w += bf2f(u[j].w);
        }
    }
    for (; e < e1; ++e) {
        const ushort4 u = Bv[(size_t)cs[e] * 16 + f4];
        acc.x += bf2f(u.x); acc.y += bf2f(u.y);
        acc.z += bf2f(u.z); acc.w += bf2f(u.w);
    }
    ushort4 o;
    o.x = f2bf(acc.x); o.y = f2bf(acc.y); o.z = f2bf(acc.z); o.w = f2bf(acc.w);
    ((ushort4*)out)[(size_t)r * 16 + f4] = o;
}

// ---------------- Final aggregation: f32 output (no GEMM epilogue) ----------
__global__ __launch_bounds__(256) void k_aggw(const ushort* __restrict__ B,
                                              const int* __restrict__ rp,
                                              const int* __restrict__ cs,
                                              float* __restrict__ out, int N) {
    const int t = threadIdx.x;
    const int gw = (blockIdx.x * 256 + t) >> 6;
    const int lane = t & 63;
    const int f4 = lane & 15;
    const int r = gw * 4 + (lane >> 4);
    if (r >= N) return;

    const int e0 = rp[r];
    const int e1 = rp[r + 1];
    const ushort4* Bv = (const ushort4*)B;

    float4 acc = make_float4(0.f, 0.f, 0.f, 0.f);
    int e = e0;
    for (; e + 7 < e1; e += 8) {
        ushort4 u[8];
#pragma unroll
        for (int j = 0; j < 8; ++j) u[j] = Bv[(size_t)cs[e + j] * 16 + f4];
#pragma unroll
        for (int j = 0; j < 8; ++j) {
            acc.x += bf2f(u[j].x); acc.y += bf2f(u[j].y);
            acc.z += bf2f(u[j].z); acc.w += bf2f(u[j].w);
        }
    }
    for (; e + 3 < e1; e += 4) {
        ushort4 u[4];
#pragma unroll
        for (int j = 0; j < 4; ++j) u[j] = Bv[(size_t)cs[e + j] * 16 + f4];
#pragma unroll
        for (int j = 0; j < 4; ++j) {
            acc.x += bf2f(u[j].x); acc.y += bf2f(u[j].y);
            acc.z += bf2f(u[j].z); acc.w += bf2f(u[j].w);
        }
    }
    for (; e < e1; ++e) {
        const ushort4 u = Bv[(size_t)cs[e] * 16 + f4];
        acc.x += bf2f(u.x); acc.y += bf2f(u.y);
        acc.z += bf2f(u.z); acc.w += bf2f(u.w);
    }
    ((float4*)out)[(size_t)r * 16 + f4] = acc;
}

// ---------------- R1 fallback kernels ----------------
__global__ __launch_bounds__(256) void gcn_gemm64(const float* __restrict__ X,
                                                  const float* __restrict__ W,
                                                  float* __restrict__ H,
                                                  int nrows) {
    __shared__ float Wl[64 * 64];
    __shared__ float Xl[16][65];
    const int tid = threadIdx.x;
    for (int i = tid; i < 1024; i += 256) ((float4*)Wl)[i] = ((const float4*)W)[i];
    const int rowBase = blockIdx.x * 16;
    const int lr = tid >> 4;
    const int lc = tid & 15;
    const int grow = rowBase + lr;
    if (grow < nrows) {
        float4 xv = ((const float4*)X)[(long long)grow * 16 + lc];
        Xl[lr][lc * 4 + 0] = xv.x; Xl[lr][lc * 4 + 1] = xv.y;
        Xl[lr][lc * 4 + 2] = xv.z; Xl[lr][lc * 4 + 3] = xv.w;
    }
    __syncthreads();
    float4 acc = make_float4(0.f, 0.f, 0.f, 0.f);
#pragma unroll
    for (int k = 0; k < 64; ++k) {
        const float xv = Xl[lr][k];
        const float4 w4 = ((float4*)Wl)[k * 16 + lc];
        acc.x = fmaf(xv, w4.x, acc.x); acc.y = fmaf(xv, w4.y, acc.y);
        acc.z = fmaf(xv, w4.z, acc.z); acc.w = fmaf(xv, w4.w, acc.w);
    }
    if (grow < nrows) ((float4*)H)[(long long)grow * 16 + lc] = acc;
}

__global__ __launch_bounds__(256) void gcn_scatter(const float* __restrict__ H,
                                                   const int* __restrict__ ei,
                                                   float* __restrict__ out,
                                                   int nedges) {
    const long long t = (long long)blockIdx.x * 256 + threadIdx.x;
    const int e = (int)(t >> 4);
    if (e >= nedges) return;
    const int lc = (int)(t & 15);
    const int s = ei[e];
    const int d = ei[nedges + e];
    const float4 v = ((const float4*)H)[(long long)s * 16 + lc];
    float* o = out + (long long)d * GCN_D + lc * 4;
    atomicAdd(o + 0, v.x);
    atomicAdd(o + 1, v.y);
    atomicAdd(o + 2, v.z);
    atomicAdd(o + 3, v.w);
}

extern "C" void kernel_launch(void* const* d_in, const int* in_sizes, int n_in,
                              void* d_out, int out_size, void* d_ws, size_t ws_size,
                              hipStream_t stream) {
    const float* x  = (const float*)d_in[0];
    const int*   ei = (const int*)d_in[1];   // [2,E] flat: src then dst (int32)
    const float* W0 = (const float*)d_in[2];
    const float* W1 = (const float*)d_in[3];
    const float* W2 = (const float*)d_in[4];
    float* out = (float*)d_out;

    const int N_ = in_sizes[0] / GCN_D;
    const int E_ = in_sizes[1] / 2;
    const int NSEG = (N_ + SEGROWS - 1) >> SEGSHIFT;

    // ws layout:
    //   B0 (N*64 bf16) | REG (max(N*64 bf16, E*4) -- B1 and ebuf alias, disjoint
    //   lifetimes) | rp (N+2) | gOff (MAXSEG+1) | ghist (MAXSEG) | gcur (MAXSEG)
    //   | Wc (4096 f32) | cs (E int)
    uintptr_t base = (uintptr_t)d_ws;
    ushort* B0 = (ushort*)base;
    const size_t bfBytes  = (size_t)N_ * GCN_D * 2;
    const size_t regBytes = bfBytes > (size_t)E_ * 4 ? bfBytes : (size_t)E_ * 4;
    ushort*   B1   = (ushort*)(base + bfBytes);
    unsigned* ebuf = (unsigned*)B1;          // alias: dead before first k_aggc
    int* rp    = (int*)(base + bfBytes + regBytes);
    int* gOff  = rp + (N_ + 2);
    int* ghist = gOff + (MAXSEG + 1);
    int* gcur  = ghist + MAXSEG;
    float* Wc  = (float*)(gcur + MAXSEG);
    int* cs    = (int*)(Wc + 4096);
    const size_t needed = ((uintptr_t)(cs + E_) - base);

    const int gemmBlocks = (N_ + 15) / 16;

    if (NSEG <= MAXSEG && N_ < (1 << 24) && ws_size >= needed) {
        k_wchain<<<1, 256, 0, stream>>>(W0, W1, W2, Wc, ghist);
        k_gemmcvt<<<gemmBlocks, 256, 0, stream>>>(x, Wc, B0, N_);
        k_a0<<<512, 256, 0, stream>>>(ei, ghist, E_);
        k_ascan<<<1, MAXSEG, 0, stream>>>(ghist, gOff, gcur, rp, N_, E_);
        k_apart<<<(E_ + A_EPB - 1) / A_EPB, 512, 0, stream>>>(ei, gcur, ebuf, E_);
        k_bplace<<<NSEG, SEGROWS, 0, stream>>>(ebuf, gOff, rp, cs, N_);

        const int aggBlocks = (N_ + 15) / 16;     // 4 rows/wave, 4 waves/block
        k_aggc<<<aggBlocks, 256, 0, stream>>>(B0, rp, cs, B1, N_);   // a1
        k_aggc<<<aggBlocks, 256, 0, stream>>>(B1, rp, cs, B0, N_);   // a2
        k_aggw<<<aggBlocks, 256, 0, stream>>>(B0, rp, cs, out, N_);  // a3 -> f32
    } else {
        // Fallback: R1 path (needs only h = N*64 f32).
        float* h = (float*)d_ws;
        const int scatBlocks = (int)(((long long)E_ * 16 + 255) / 256);
        const float* curAct = x;
        for (int l = 0; l < 3; ++l) {
            const float* Wl = (l == 0) ? W0 : (l == 1) ? W1 : W2;
            gcn_gemm64<<<gemmBlocks, 256, 0, stream>>>(curAct, Wl, h, N_);
            hipMemsetAsync(out, 0, (size_t)N_ * GCN_D * sizeof(float), stream);
            gcn_scatter<<<scatBlocks, 256, 0, stream>>>(h, ei, out, E_);
            curAct = out;
        }
    }
}

// Round 10
// 169.425 us; speedup vs baseline: 8.6451x; 1.0173x over previous
//
#include <hip/hip_runtime.h>

// 3-layer GCN on MI355X:  out = S^3(x · (W0 W1 W2)),  S = scatter-add over E edges.
// N = 100000, E = 1200000, D = 64.
//
// Per launch (7 dispatches, no cross-call state):
//   k_wchain  : Wc = W0 @ W1 @ W2; zero ghist + csr0   (1 block)
//   k_gemmcvt : B0 = bf16(x @ Wc); first 512 blocks also histogram dst segments
//   k_apart   : local scan of ghist + LDS counting-sort 4096-edge blocks ->
//               packed (src<<8|lr) per-segment runs (cursor = csr0)
//   k_bplace  : local scan + per-segment LDS counting sort -> rp + cs
//   k_aggc2   : agg layer 1 (8 lanes x 16 B, 8 rows/wave)   [A/B probe]
//   k_aggc    : agg layer 2 (16 lanes x 8 B, 4 rows/wave)   [A/B probe]
//   k_aggw    : agg layer 3, f32 output

#define GCN_D 64
#define SEGSHIFT 8
#define SEGROWS 256          // dst rows per segment
#define MAXSEG 512           // compile-time LDS capacity (N <= 131072)
#define A_EPB 4096           // edges per k_apart block
#define HISTB 512            // gemmcvt blocks that also histogram

typedef unsigned short ushort;

__device__ __forceinline__ float bf2f(ushort u) {
    union { unsigned u; float f; } c; c.u = ((unsigned)u) << 16; return c.f;
}
__device__ __forceinline__ float bflo(unsigned u) {
    union { unsigned u; float f; } c; c.u = u << 16; return c.f;
}
__device__ __forceinline__ float bfhi(unsigned u) {
    union { unsigned u; float f; } c; c.u = u & 0xFFFF0000u; return c.f;
}
// RNE f32 -> bf16 (finite inputs): add 0x7FFF + lsb(bit16), truncate.
__device__ __forceinline__ ushort f2bf(float f) {
    union { float f; unsigned u; } c; c.f = f;
    const unsigned r = 0x7FFFu + ((c.u >> 16) & 1u);
    return (ushort)((c.u + r) >> 16);
}
__device__ __forceinline__ unsigned pack2(float a, float b) {
    return (unsigned)f2bf(a) | ((unsigned)f2bf(b) << 16);
}

// ---------------- Wc = W0 @ W1 @ W2 (single block); zero ghist/csr0 ----------
__global__ __launch_bounds__(256) void k_wchain(const float* __restrict__ W0,
                                                const float* __restrict__ W1,
                                                const float* __restrict__ W2,
                                                float* __restrict__ Wc,
                                                int* __restrict__ ghist,
                                                int* __restrict__ csr0) {
    __shared__ float A[4096], B[4096], T[4096];
    const int t = threadIdx.x;
    for (int i = t; i < MAXSEG; i += 256) { ghist[i] = 0; csr0[i] = 0; }
    for (int i = t; i < 1024; i += 256) {
        ((float4*)A)[i] = ((const float4*)W0)[i];
        ((float4*)B)[i] = ((const float4*)W1)[i];
    }
    __syncthreads();
#pragma unroll
    for (int g = 0; g < 4; ++g) {
        const int idx = t + 256 * g;
        const int r = idx >> 4, c4 = idx & 15;
        float4 acc = make_float4(0.f, 0.f, 0.f, 0.f);
#pragma unroll
        for (int k = 0; k < 64; ++k) {
            const float a = A[r * 64 + k];
            const float4 b = ((float4*)B)[k * 16 + c4];
            acc.x = fmaf(a, b.x, acc.x); acc.y = fmaf(a, b.y, acc.y);
            acc.z = fmaf(a, b.z, acc.z); acc.w = fmaf(a, b.w, acc.w);
        }
        ((float4*)T)[idx] = acc;
    }
    __syncthreads();
    for (int i = t; i < 1024; i += 256) ((float4*)B)[i] = ((const float4*)W2)[i];
    __syncthreads();
#pragma unroll
    for (int g = 0; g < 4; ++g) {
        const int idx = t + 256 * g;
        const int r = idx >> 4, c4 = idx & 15;
        float4 acc = make_float4(0.f, 0.f, 0.f, 0.f);
#pragma unroll
        for (int k = 0; k < 64; ++k) {
            const float a = T[r * 64 + k];
            const float4 b = ((float4*)B)[k * 16 + c4];
            acc.x = fmaf(a, b.x, acc.x); acc.y = fmaf(a, b.y, acc.y);
            acc.z = fmaf(a, b.z, acc.z); acc.w = fmaf(a, b.w, acc.w);
        }
        ((float4*)Wc)[idx] = acc;
    }
}

// ---------------- GEMM + convert (+ fused segment histogram) ----------------
__global__ __launch_bounds__(256) void k_gemmcvt(const float* __restrict__ X,
                                                 const float* __restrict__ Wc,
                                                 ushort* __restrict__ B,
                                                 const int* __restrict__ ei,
                                                 int* __restrict__ ghist,
                                                 int nrows, int E) {
    __shared__ float Wl[4096];
    __shared__ float Xl[16][65];
    __shared__ int h[MAXSEG];
    const int tid = threadIdx.x;
    for (int i = tid; i < 1024; i += 256) ((float4*)Wl)[i] = ((const float4*)Wc)[i];

    const int lr = tid >> 4;
    const int lc = tid & 15;
    const int grow = blockIdx.x * 16 + lr;

    if (grow < nrows) {
        const float4 xv = ((const float4*)X)[(size_t)grow * 16 + lc];
        Xl[lr][lc * 4 + 0] = xv.x; Xl[lr][lc * 4 + 1] = xv.y;
        Xl[lr][lc * 4 + 2] = xv.z; Xl[lr][lc * 4 + 3] = xv.w;
    }
    __syncthreads();

    float4 acc = make_float4(0.f, 0.f, 0.f, 0.f);
#pragma unroll
    for (int k = 0; k < 64; ++k) {
        const float xv = Xl[lr][k];
        const float4 w4 = ((const float4*)Wl)[k * 16 + lc];
        acc.x = fmaf(xv, w4.x, acc.x); acc.y = fmaf(xv, w4.y, acc.y);
        acc.z = fmaf(xv, w4.z, acc.z); acc.w = fmaf(xv, w4.w, acc.w);
    }
    if (grow < nrows) {
        ushort4 o;
        o.x = f2bf(acc.x); o.y = f2bf(acc.y); o.z = f2bf(acc.z); o.w = f2bf(acc.w);
        ((ushort4*)B)[(size_t)grow * 16 + lc] = o;
    }

    // fused segment histogram (first HISTB blocks only; LDS-aggregated)
    if (blockIdx.x < HISTB) {
        for (int i = tid; i < MAXSEG; i += 256) h[i] = 0;
        __syncthreads();
        for (int e = blockIdx.x * 256 + tid; e < E; e += HISTB * 256)
            atomicAdd(&h[ei[E + e] >> SEGSHIFT], 1);
        __syncthreads();
        for (int i = tid; i < MAXSEG; i += 256) {
            const int c = h[i];
            if (c) atomicAdd(&ghist[i], c);
        }
    }
}

// ---------------- A-partition: local scan + LDS counting sort ----------------
// Packed word: (src << 8) | (dst & 255). src < 2^24 required.
__global__ __launch_bounds__(512) void k_apart(const int* __restrict__ ei,
                                               const int* __restrict__ ghist,
                                               int* __restrict__ csr0,
                                               unsigned* __restrict__ ebuf, int E) {
    __shared__ int hist[MAXSEG], lofs[MAXSEG], cur[MAXSEG], gbase[MAXSEG], goffx[MAXSEG];
    __shared__ unsigned stg[A_EPB];
    __shared__ ushort stg2[A_EPB];
    const int t = threadIdx.x;
    const int base = blockIdx.x * A_EPB;
    const int cnt = min(A_EPB, E - base);

    // global exclusive offsets: scan ghist (512) locally
    const int gv = ghist[t];
    goffx[t] = gv; __syncthreads();
    for (int off = 1; off < MAXSEG; off <<= 1) {
        const int y = (t >= off) ? goffx[t - off] : 0;
        __syncthreads();
        goffx[t] += y;
        __syncthreads();
    }
    const int gexcl = goffx[t] - gv;
    goffx[t] = gexcl;                   // own slot only; no cross-read after scan
    hist[t] = 0;
    __syncthreads();

    unsigned my[8]; int mb[8];
#pragma unroll
    for (int j = 0; j < 8; ++j) {
        const int i = t + j * 512;
        if (i < cnt) {
            const int e = base + i;
            const unsigned s = (unsigned)ei[e];
            const unsigned d = (unsigned)ei[E + e];
            my[j] = (s << 8) | (d & (SEGROWS - 1));
            mb[j] = (int)(d >> SEGSHIFT);
            atomicAdd(&hist[mb[j]], 1);
        } else mb[j] = -1;
    }
    __syncthreads();

    // exclusive block scan of hist -> lofs (and cursor copy)
    {
        const int v = hist[t];
        lofs[t] = v; __syncthreads();
        for (int off = 1; off < MAXSEG; off <<= 1) {
            const int y = (t >= off) ? lofs[t - off] : 0;
            __syncthreads();
            lofs[t] += y;
            __syncthreads();
        }
        const int excl = lofs[t] - v;
        __syncthreads();
        lofs[t] = excl; cur[t] = excl;
    }
    __syncthreads();

    // place packed words into stg grouped by segment; remember segment id
#pragma unroll
    for (int j = 0; j < 8; ++j) {
        if (mb[j] >= 0) {
            const int p = atomicAdd(&cur[mb[j]], 1);
            stg[p] = my[j];
            stg2[p] = (ushort)mb[j];
        }
    }
    __syncthreads();

    // reserve global space per segment (zero-based cursor + local global offset)
    {
        const int c = hist[t];
        const int p = c ? atomicAdd(&csr0[t], c) : 0;
        gbase[t] = goffx[t] + p;
    }
    __syncthreads();

    // copy runs out (consecutive i within a run -> coalesced global writes)
    for (int i = t; i < cnt; i += 512) {
        const int b = (int)stg2[i];
        ebuf[(size_t)gbase[b] + (unsigned)(i - lofs[b])] = stg[i];
    }
}

// ---------------- B-place: local scan + per-segment counting sort ------------
__global__ __launch_bounds__(SEGROWS) void k_bplace(const unsigned* __restrict__ ebuf,
                                                    const int* __restrict__ ghist,
                                                    int* __restrict__ rp,
                                                    int* __restrict__ cs, int N, int E) {
    __shared__ int h[SEGROWS], ofs[SEGROWS], gpart[SEGROWS];
    __shared__ int gx[MAXSEG];
    const int s = blockIdx.x;
    const int t = threadIdx.x;

    // exclusive scan of ghist (512 entries, 2 per thread) -> gx
    const int a0 = ghist[2 * t];
    const int a1 = ghist[2 * t + 1];
    const int ps = a0 + a1;
    gpart[t] = ps; __syncthreads();
    for (int off = 1; off < SEGROWS; off <<= 1) {
        const int y = (t >= off) ? gpart[t - off] : 0;
        __syncthreads();
        gpart[t] += y;
        __syncthreads();
    }
    const int ex = gpart[t] - ps;
    gx[2 * t] = ex;
    gx[2 * t + 1] = ex + a0;
    if (s == 0 && t == 0) rp[N] = E;
    __syncthreads();

    const int e0 = gx[s];
    const int e1 = e0 + ghist[s];

    h[t] = 0; __syncthreads();
    for (int e = e0 + t; e < e1; e += SEGROWS)
        atomicAdd(&h[ebuf[e] & (SEGROWS - 1)], 1);
    __syncthreads();

    const int v = h[t];
    ofs[t] = v; __syncthreads();
    for (int off = 1; off < SEGROWS; off <<= 1) {
        const int y = (t >= off) ? ofs[t - off] : 0;
        __syncthreads();
        ofs[t] += y;
        __syncthreads();
    }
    const int excl = ofs[t] - v;
    const int r = s * SEGROWS + t;
    if (r < N) rp[r] = e0 + excl;
    __syncthreads();
    ofs[t] = excl;                 // becomes the within-segment cursor
    __syncthreads();

    for (int e = e0 + t; e < e1; e += SEGROWS) {
        const unsigned pr = ebuf[e];
        const int lr = (int)(pr & (SEGROWS - 1));
        const int p = atomicAdd(&ofs[lr], 1);
        cs[e0 + p] = (int)(pr >> 8);
    }
}

// ---------------- Agg variant A: 8 lanes x 16 B, 8 rows/wave -----------------
__global__ __launch_bounds__(256) void k_aggc2(const ushort* __restrict__ B,
                                               const int* __restrict__ rp,
                                               const int* __restrict__ cs,
                                               ushort* __restrict__ out, int N) {
    const int t = threadIdx.x;
    const int gw = (blockIdx.x * 256 + t) >> 6;
    const int lane = t & 63;
    const int f8 = lane & 7;                   // 16 B slot in row
    const int r = gw * 8 + (lane >> 3);
    if (r >= N) return;

    const int e0 = rp[r];
    const int e1 = rp[r + 1];
    const uint4* Bv = (const uint4*)B;

    float acc[8] = {0.f, 0.f, 0.f, 0.f, 0.f, 0.f, 0.f, 0.f};
    int e = e0;
    for (; e + 7 < e1; e += 8) {
        uint4 u[8];
#pragma unroll
        for (int j = 0; j < 8; ++j) u[j] = Bv[(size_t)cs[e + j] * 8 + f8];
#pragma unroll
        for (int j = 0; j < 8; ++j) {
            acc[0] += bflo(u[j].x); acc[1] += bfhi(u[j].x);
            acc[2] += bflo(u[j].y); acc[3] += bfhi(u[j].y);
            acc[4] += bflo(u[j].z); acc[5] += bfhi(u[j].z);
            acc[6] += bflo(u[j].w); acc[7] += bfhi(u[j].w);
        }
    }
    for (; e < e1; ++e) {
        const uint4 u = Bv[(size_t)cs[e] * 8 + f8];
        acc[0] += bflo(u.x); acc[1] += bfhi(u.x);
        acc[2] += bflo(u.y); acc[3] += bfhi(u.y);
        acc[4] += bflo(u.z); acc[5] += bfhi(u.z);
        acc[6] += bflo(u.w); acc[7] += bfhi(u.w);
    }
    uint4 o;
    o.x = pack2(acc[0], acc[1]); o.y = pack2(acc[2], acc[3]);
    o.z = pack2(acc[4], acc[5]); o.w = pack2(acc[6], acc[7]);
    ((uint4*)out)[(size_t)r * 8 + f8] = o;
}

// ---------------- Agg variant B: 16 lanes x 8 B, 4 rows/wave -----------------
__global__ __launch_bounds__(256) void k_aggc(const ushort* __restrict__ B,
                                              const int* __restrict__ rp,
                                              const int* __restrict__ cs,
                                              ushort* __restrict__ out, int N) {
    const int t = threadIdx.x;
    const int gw = (blockIdx.x * 256 + t) >> 6;
    const int lane = t & 63;
    const int f4 = lane & 15;
    const int r = gw * 4 + (lane >> 4);
    if (r >= N) return;

    const int e0 = rp[r];
    const int e1 = rp[r + 1];
    const ushort4* Bv = (const ushort4*)B;

    float4 acc = make_float4(0.f, 0.f, 0.f, 0.f);
    int e = e0;
    for (; e + 7 < e1; e += 8) {
        ushort4 u[8];
#pragma unroll
        for (int j = 0; j < 8; ++j) u[j] = Bv[(size_t)cs[e + j] * 16 + f4];
#pragma unroll
        for (int j = 0; j < 8; ++j) {
            acc.x += bf2f(u[j].x); acc.y += bf2f(u[j].y);
            acc.z += bf2f(u[j].z); acc.w += bf2f(u[j].w);
        }
    }
    for (; e + 3 < e1; e += 4) {
        ushort4 u[4];
#pragma unroll
        for (int j = 0; j < 4; ++j) u[j] = Bv[(size_t)cs[e + j] * 16 + f4];
#pragma unroll
        for (int j = 0; j < 4; ++j) {
            acc.x += bf2f(u[j].x); acc.y += bf2f(u[j].y);
            acc.z += bf2f(u[j].z); acc.w += bf2f(u[j].w);
        }
    }
    for (; e < e1; ++e) {
        const ushort4 u = Bv[(size_t)cs[e] * 16 + f4];
        acc.x += bf2f(u.x); acc.y += bf2f(u.y);
        acc.z += bf2f(u.z); acc.w += bf2f(u.w);
    }
    ushort4 o;
    o.x = f2bf(acc.x); o.y = f2bf(acc.y); o.z = f2bf(acc.z); o.w = f2bf(acc.w);
    ((ushort4*)out)[(size_t)r * 16 + f4] = o;
}

// ---------------- Final aggregation: f32 output ------------------------------
__global__ __launch_bounds__(256) void k_aggw(const ushort* __restrict__ B,
                                              const int* __restrict__ rp,
                                              const int* __restrict__ cs,
                                              float* __restrict__ out, int N) {
    const int t = threadIdx.x;
    const int gw = (blockIdx.x * 256 + t) >> 6;
    const int lane = t & 63;
    const int f4 = lane & 15;
    const int r = gw * 4 + (lane >> 4);
    if (r >= N) return;

    const int e0 = rp[r];
    const int e1 = rp[r + 1];
    const ushort4* Bv = (const ushort4*)B;

    float4 acc = make_float4(0.f, 0.f, 0.f, 0.f);
    int e = e0;
    for (; e + 7 < e1; e += 8) {
        ushort4 u[8];
#pragma unroll
        for (int j = 0; j < 8; ++j) u[j] = Bv[(size_t)cs[e + j] * 16 + f4];
#pragma unroll
        for (int j = 0; j < 8; ++j) {
            acc.x += bf2f(u[j].x); acc.y += bf2f(u[j].y);
            acc.z += bf2f(u[j].z); acc.w += bf2f(u[j].w);
        }
    }
    for (; e + 3 < e1; e += 4) {
        ushort4 u[4];
#pragma unroll
        for (int j = 0; j < 4; ++j) u[j] = Bv[(size_t)cs[e + j] * 16 + f4];
#pragma unroll
        for (int j = 0; j < 4; ++j) {
            acc.x += bf2f(u[j].x); acc.y += bf2f(u[j].y);
            acc.z += bf2f(u[j].z); acc.w += bf2f(u[j].w);
        }
    }
    for (; e < e1; ++e) {
        const ushort4 u = Bv[(size_t)cs[e] * 16 + f4];
        acc.x += bf2f(u.x); acc.y += bf2f(u.y);
        acc.z += bf2f(u.z); acc.w += bf2f(u.w);
    }
    ((float4*)out)[(size_t)r * 16 + f4] = acc;
}

// ---------------- R1 fallback kernels ----------------
__global__ __launch_bounds__(256) void gcn_gemm64(const float* __restrict__ X,
                                                  const float* __restrict__ W,
                                                  float* __restrict__ H,
                                                  int nrows) {
    __shared__ float Wl[64 * 64];
    __shared__ float Xl[16][65];
    const int tid = threadIdx.x;
    for (int i = tid; i < 1024; i += 256) ((float4*)Wl)[i] = ((const float4*)W)[i];
    const int rowBase = blockIdx.x * 16;
    const int lr = tid >> 4;
    const int lc = tid & 15;
    const int grow = rowBase + lr;
    if (grow < nrows) {
        float4 xv = ((const float4*)X)[(long long)grow * 16 + lc];
        Xl[lr][lc * 4 + 0] = xv.x; Xl[lr][lc * 4 + 1] = xv.y;
        Xl[lr][lc * 4 + 2] = xv.z; Xl[lr][lc * 4 + 3] = xv.w;
    }
    __syncthreads();
    float4 acc = make_float4(0.f, 0.f, 0.f, 0.f);
#pragma unroll
    for (int k = 0; k < 64; ++k) {
        const float xv = Xl[lr][k];
        const float4 w4 = ((float4*)Wl)[k * 16 + lc];
        acc.x = fmaf(xv, w4.x, acc.x); acc.y = fmaf(xv, w4.y, acc.y);
        acc.z = fmaf(xv, w4.z, acc.z); acc.w = fmaf(xv, w4.w, acc.w);
    }
    if (grow < nrows) ((float4*)H)[(long long)grow * 16 + lc] = acc;
}

__global__ __launch_bounds__(256) void gcn_scatter(const float* __restrict__ H,
                                                   const int* __restrict__ ei,
                                                   float* __restrict__ out,
                                                   int nedges) {
    const long long t = (long long)blockIdx.x * 256 + threadIdx.x;
    const int e = (int)(t >> 4);
    if (e >= nedges) return;
    const int lc = (int)(t & 15);
    const int s = ei[e];
    const int d = ei[nedges + e];
    const float4 v = ((const float4*)H)[(long long)s * 16 + lc];
    float* o = out + (long long)d * GCN_D + lc * 4;
    atomicAdd(o + 0, v.x);
    atomicAdd(o + 1, v.y);
    atomicAdd(o + 2, v.z);
    atomicAdd(o + 3, v.w);
}

extern "C" void kernel_launch(void* const* d_in, const int* in_sizes, int n_in,
                              void* d_out, int out_size, void* d_ws, size_t ws_size,
                              hipStream_t stream) {
    const float* x  = (const float*)d_in[0];
    const int*   ei = (const int*)d_in[1];   // [2,E] flat: src then dst (int32)
    const float* W0 = (const float*)d_in[2];
    const float* W1 = (const float*)d_in[3];
    const float* W2 = (const float*)d_in[4];
    float* out = (float*)d_out;

    const int N_ = in_sizes[0] / GCN_D;
    const int E_ = in_sizes[1] / 2;
    const int NSEG = (N_ + SEGROWS - 1) >> SEGSHIFT;

    // ws layout:
    //   B0 (N*64 bf16) | REG (max(N*64 bf16, E*4) -- B1/ebuf alias, disjoint
    //   lifetimes) | rp (N+2) | ghist (512) | csr0 (512) | Wc (4096 f32) | cs (E)
    uintptr_t base = (uintptr_t)d_ws;
    ushort* B0 = (ushort*)base;
    const size_t bfBytes  = (size_t)N_ * GCN_D * 2;
    const size_t regBytes = bfBytes > (size_t)E_ * 4 ? bfBytes : (size_t)E_ * 4;
    ushort*   B1   = (ushort*)(base + bfBytes);
    unsigned* ebuf = (unsigned*)B1;          // alias: dead before first agg
    int* rp    = (int*)(base + bfBytes + regBytes);
    int* ghist = rp + (N_ + 2);
    int* csr0  = ghist + MAXSEG;
    float* Wc  = (float*)(csr0 + MAXSEG);
    int* cs    = (int*)(Wc + 4096);
    const size_t needed = ((uintptr_t)(cs + E_) - base);

    const int gemmBlocks = (N_ + 15) / 16;
    const int gcBlocks = gemmBlocks > HISTB ? gemmBlocks : HISTB;

    if (NSEG <= MAXSEG && N_ < (1 << 24) && ws_size >= needed) {
        k_wchain<<<1, 256, 0, stream>>>(W0, W1, W2, Wc, ghist, csr0);
        k_gemmcvt<<<gcBlocks, 256, 0, stream>>>(x, Wc, B0, ei, ghist, N_, E_);
        k_apart<<<(E_ + A_EPB - 1) / A_EPB, 512, 0, stream>>>(ei, ghist, csr0, ebuf, E_);
        k_bplace<<<NSEG, SEGROWS, 0, stream>>>(ebuf, ghist, rp, cs, N_, E_);

        const int aggBlocks  = (N_ + 15) / 16;    // 4 rows/wave
        const int aggBlocks2 = (N_ + 31) / 32;    // 8 rows/wave
        k_aggc2<<<aggBlocks2, 256, 0, stream>>>(B0, rp, cs, B1, N_);  // a1 (16B/lane)
        k_aggc <<<aggBlocks,  256, 0, stream>>>(B1, rp, cs, B0, N_);  // a2 (8B/lane)
        k_aggw <<<aggBlocks,  256, 0, stream>>>(B0, rp, cs, out, N_); // a3 -> f32
    } else {
        // Fallback: R1 path (needs only h = N*64 f32).
        float* h = (float*)d_ws;
        const int scatBlocks = (int)(((long long)E_ * 16 + 255) / 256);
        const float* curAct = x;
        for (int l = 0; l < 3; ++l) {
            const float* Wl = (l == 0) ? W0 : (l == 1) ? W1 : W2;
            gcn_gemm64<<<gemmBlocks, 256, 0, stream>>>(curAct, Wl, h, N_);
            hipMemsetAsync(out, 0, (size_t)N_ * GCN_D * sizeof(float), stream);
            gcn_scatter<<<scatBlocks, 256, 0, stream>>>(h, ei, out, E_);
            curAct = out;
        }
    }
}